// Round 7
// baseline (551.016 us; speedup 1.0000x reference)
//
#include <hip/hip_runtime.h>
#include <cstdint>
#include <cstddef>

#define NN 50000
#define NE 800000
#define DD 128

static_assert(NN % 16 == 0, "node tiles");
static_assert(NE % 16 == 0, "edge tiles");

typedef __bf16 bf16_t;
typedef bf16_t bf16x8 __attribute__((ext_vector_type(8)));
typedef bf16_t bf16x4 __attribute__((ext_vector_type(4)));
typedef bf16_t bf16x2 __attribute__((ext_vector_type(2)));
typedef float f32x4 __attribute__((ext_vector_type(4)));

// fast gelu: x * sigmoid(2*0.79788456*(x+0.044715x^3)) via v_exp_f32 + rcp (~1e-3 abs err)
__device__ __forceinline__ float gelu_f(float x) {
    float u = x * x;
    float t = fmaf(u, -0.1029442445f, -2.3021184019f);  // -(2log2e)*0.79788456*(1+0.044715u)
    float s = __builtin_amdgcn_exp2f(x * t);
    return x * __builtin_amdgcn_rcpf(1.0f + s);
}

// ---------------- feat f32 -> bf16 ----------------
__global__ __launch_bounds__(256) void convert_feat_kernel(
    const float* __restrict__ feat, bf16_t* __restrict__ fb)
{
    int i = blockIdx.x * 256 + threadIdx.x;  // quad index; NN*DD/4 = 1.6M exact
    f32x4 v = ((const f32x4*)feat)[i];
    bf16x4 o;
    o[0] = (bf16_t)v[0]; o[1] = (bf16_t)v[1]; o[2] = (bf16_t)v[2]; o[3] = (bf16_t)v[3];
    ((bf16x4*)fb)[i] = o;
}

// ---------------- prep: combine + convert weights, combine biases ----------------
__global__ __launch_bounds__(256) void prep_kernel(
    const float* __restrict__ W_asrc, const float* __restrict__ b_asrc,
    const float* __restrict__ W_adst, const float* __restrict__ b_adst,
    const float* __restrict__ W_asub, const float* __restrict__ b_asub,
    const float* __restrict__ W_amul, const float* __restrict__ b_amul,
    const float* __restrict__ W_pool, const float* __restrict__ W_pool2,
    const float* __restrict__ W_self, const float* __restrict__ b_self,
    const float* __restrict__ W_neigh, const float* __restrict__ b_neigh,
    const float* __restrict__ W_neigh2, const float* __restrict__ b_neigh2,
    const float* __restrict__ W_mlp,
    bf16_t* __restrict__ W_S, bf16_t* __restrict__ W_D, bf16_t* __restrict__ W_amulb,
    bf16_t* __restrict__ W_poolb, bf16_t* __restrict__ W_pool2b,
    bf16_t* __restrict__ W_selfb, bf16_t* __restrict__ W_neighb, bf16_t* __restrict__ W_neigh2b,
    bf16_t* __restrict__ W_mlpb,
    float* __restrict__ b_e, float* __restrict__ b_rst)
{
    int gid = blockIdx.x * 256 + threadIdx.x;  // 64 blocks * 256 = 16384 = DD*DD
    float sub = W_asub[gid];
    W_S[gid] = (bf16_t)(W_asrc[gid] + sub);
    W_D[gid] = (bf16_t)(W_adst[gid] - sub);
    W_amulb[gid]   = (bf16_t)W_amul[gid];
    W_poolb[gid]   = (bf16_t)W_pool[gid];
    W_pool2b[gid]  = (bf16_t)W_pool2[gid];
    W_selfb[gid]   = (bf16_t)W_self[gid];
    W_neighb[gid]  = (bf16_t)W_neigh[gid];
    W_neigh2b[gid] = (bf16_t)W_neigh2[gid];
    W_mlpb[gid]            = (bf16_t)W_mlp[gid];
    W_mlpb[DD * DD + gid]  = (bf16_t)W_mlp[DD * DD + gid];
    if (gid < DD) {
        b_e[gid]   = b_asub[gid] + b_amul[gid] + b_asrc[gid] + b_adst[gid];
        b_rst[gid] = b_self[gid] + b_neigh[gid] + b_neigh2[gid];
    }
}

// gelu + store interleaved into hh[node][256]: h ch -> (ch/2)*4+(ch&1), h2 -> +2
__device__ __forceinline__ void mm16_store_ilv(
    const bf16x8 a[4], const bf16_t* __restrict__ W, const float* __restrict__ bias,
    bf16_t* __restrict__ hh, int nb, int n, int q, int sub)
{
#pragma unroll
    for (int t = 0; t < 8; t++) {
        f32x4 acc = {0.f, 0.f, 0.f, 0.f};
#pragma unroll
        for (int kb = 0; kb < 4; kb++) {
            bf16x8 b = *(const bf16x8*)(W + (t * 16 + n) * DD + kb * 32 + q * 8);
            acc = __builtin_amdgcn_mfma_f32_16x16x32_bf16(a[kb], b, acc, 0, 0, 0);
        }
        int ch = t * 16 + n;
        int pos = ((ch >> 1) << 2) + (ch & 1) + sub;
        float bv = bias[ch];
#pragma unroll
        for (int r = 0; r < 4; r++)
            hh[(size_t)(nb + q * 4 + r) * 256 + pos] = (bf16_t)gelu_f(acc[r] + bv);
    }
}

// ---------------- per-node linears: h/h2 (interleaved) ----------------
__global__ __launch_bounds__(256) void node_linear_kernel(
    const bf16_t* __restrict__ fb,
    const bf16_t* __restrict__ W_pool, const float* __restrict__ b_pool,
    const bf16_t* __restrict__ W_pool2, const float* __restrict__ b_pool2,
    bf16_t* __restrict__ hh)
{
    int wid = blockIdx.x * 4 + (threadIdx.x >> 6);
    if (wid >= NN / 16) return;
    int lane = threadIdx.x & 63, n = lane & 15, q = lane >> 4;
    int nb = wid * 16;
    bf16x8 a[4];
#pragma unroll
    for (int kb = 0; kb < 4; kb++)
        a[kb] = *(const bf16x8*)(fb + (size_t)(nb + n) * DD + kb * 32 + q * 8);
    mm16_store_ilv(a, W_pool, b_pool, hh, nb, n, q, 0);
    mm16_store_ilv(a, W_pool2, b_pool2, hh, nb, n, q, 2);
}

// ---------------- CSR build ----------------
__global__ __launch_bounds__(256) void hist_kernel(const int* __restrict__ dst, int* __restrict__ deg) {
    int e = blockIdx.x * 256 + threadIdx.x;
    if (e < NE) atomicAdd(&deg[dst[e]], 1);
}

#define SCAN_NB ((NN + 255) / 256)  // 196

__global__ __launch_bounds__(256) void scan1_kernel(const int* __restrict__ deg,
                                                    int* __restrict__ offsets, int* __restrict__ bsum)
{
    __shared__ int tmp[256];
    int t = threadIdx.x, g = blockIdx.x * 256 + t;
    int v = (g < NN) ? deg[g] : 0;
    tmp[t] = v;
    __syncthreads();
#pragma unroll
    for (int d = 1; d < 256; d <<= 1) {
        int x = (t >= d) ? tmp[t - d] : 0;
        __syncthreads();
        tmp[t] += x;
        __syncthreads();
    }
    if (g < NN) offsets[g] = tmp[t] - v;  // local exclusive
    if (t == 255) bsum[blockIdx.x] = tmp[255];
}

__global__ __launch_bounds__(256) void scan2_kernel(const int* __restrict__ bsum, int* __restrict__ bbase)
{
    __shared__ int tmp[256];
    int t = threadIdx.x;
    int v = (t < SCAN_NB) ? bsum[t] : 0;
    tmp[t] = v;
    __syncthreads();
#pragma unroll
    for (int d = 1; d < 256; d <<= 1) {
        int x = (t >= d) ? tmp[t - d] : 0;
        __syncthreads();
        tmp[t] += x;
        __syncthreads();
    }
    if (t < SCAN_NB) bbase[t] = tmp[t] - v;
}

__global__ __launch_bounds__(256) void scan3_kernel(const int* __restrict__ bbase,
                                                    int* __restrict__ offsets, int* __restrict__ cursor)
{
    int g = blockIdx.x * 256 + threadIdx.x;
    if (g < NN) {
        int o = offsets[g] + bbase[blockIdx.x];
        offsets[g] = o;
        cursor[g] = o;
    }
}

// scatter AFTER edge_score: pack {src, score-bits} per CSR slot
__global__ __launch_bounds__(256) void scatter_kernel(
    const int* __restrict__ src, const int* __restrict__ dst, const float* __restrict__ scores,
    int* __restrict__ cursor, int2* __restrict__ csr)
{
    int e = blockIdx.x * 256 + threadIdx.x;
    if (e < NE) {
        int d = dst[e];
        int pos = atomicAdd(&cursor[d], 1);
        int2 pk;
        pk.x = src[e];
        pk.y = __float_as_int(scores[e]);
        csr[pos] = pk;
    }
}

// ---------------- per-edge score: weight-stationary, edge-streaming ----------------
// 512-thread blocks = 8 waves; wave w owns channel tile t=w (16 ch): 12 weight A-frags
// in registers for kernel lifetime. 32-edge tiles staged (fs/fd) in double-buffered LDS;
// p = fs*fd computed in B-frag layout at consume time. 2 barriers/iter.
#define ES_NBLK 1250
#define ES_ITERS (NE / 32 / ES_NBLK)   // 20

__global__ __launch_bounds__(512, 4) void edge_score_kernel(
    const bf16_t* __restrict__ fb, const int* __restrict__ src, const int* __restrict__ dst,
    const bf16_t* __restrict__ W_amul, const bf16_t* __restrict__ W_S, const bf16_t* __restrict__ W_D,
    const float* __restrict__ w_aout, const float* __restrict__ b_aout, const float* __restrict__ b_e,
    float* __restrict__ scores)
{
    __shared__ __align__(16) bf16_t sS[2][32 * 136];
    __shared__ __align__(16) bf16_t sDm[2][32 * 136];
    __shared__ float partials[32 * 8];  // [edge][wave]
    int tid = threadIdx.x;
    int wave = tid >> 6, lane = tid & 63;
    int m = lane & 15, q = lane >> 4;
    int t = wave;  // this wave's channel tile

    // persistent weight A-frags: lane holds W[ch = t*16+m][k = kb*32+q*8 .. +7]
    bf16x8 wAm[4], wSf[4], wDf[4];
#pragma unroll
    for (int kb = 0; kb < 4; kb++) {
        int wo = (t * 16 + m) * DD + kb * 32 + q * 8;
        wAm[kb] = *(const bf16x8*)(W_amul + wo);
        wSf[kb] = *(const bf16x8*)(W_S + wo);
        wDf[kb] = *(const bf16x8*)(W_D + wo);
    }
    float be[4], wa[4];
#pragma unroll
    for (int r = 0; r < 4; r++) {
        int ch = t * 16 + q * 4 + r;
        be[r] = b_e[ch];
        wa[r] = w_aout[ch];
    }
    float bout = b_aout[0];

    // staging role: thread -> edge sed (0..31), 16B chunk sc_ (0..15)
    int sed = tid >> 4, sc_ = tid & 15;

    // prefetch tile 0
    int e0 = blockIdx.x * 32 + sed;
    int ps = src[e0], pd = dst[e0];
    bf16x8 pfs = *(const bf16x8*)(fb + (size_t)ps * DD + sc_ * 8);
    bf16x8 pfd = *(const bf16x8*)(fb + (size_t)pd * DD + sc_ * 8);

    for (int it = 0; it < ES_ITERS; it++) {
        int buf = it & 1;
        int eb = (blockIdx.x + it * ES_NBLK) * 32;
        *(bf16x8*)(sS[buf] + sed * 136 + sc_ * 8) = pfs;
        *(bf16x8*)(sDm[buf] + sed * 136 + sc_ * 8) = pfd;
        __syncthreads();  // stage visible (also fences prev iter's partials reads)
        // software pipeline: issue next tile's gathers now
        if (it + 1 < ES_ITERS) {
            int e1 = (blockIdx.x + (it + 1) * ES_NBLK) * 32 + sed;
            ps = src[e1]; pd = dst[e1];
            pfs = *(const bf16x8*)(fb + (size_t)ps * DD + sc_ * 8);
            pfd = *(const bf16x8*)(fb + (size_t)pd * DD + sc_ * 8);
        }
        // two 16-edge groups
#pragma unroll
        for (int g = 0; g < 2; g++) {
            bf16x8 bS[4], bD[4];
#pragma unroll
            for (int kb = 0; kb < 4; kb++) {
                int off = (g * 16 + m) * 136 + kb * 32 + q * 8;
                bS[kb] = *(const bf16x8*)(sS[buf] + off);
                bD[kb] = *(const bf16x8*)(sDm[buf] + off);
            }
            f32x4 acc = {0.f, 0.f, 0.f, 0.f};
#pragma unroll
            for (int kb = 0; kb < 4; kb++) {
                bf16x8 bP;
#pragma unroll
                for (int j = 0; j < 8; j++) bP[j] = (bf16_t)((float)bS[kb][j] * (float)bD[kb][j]);
                acc = __builtin_amdgcn_mfma_f32_16x16x32_bf16(wAm[kb], bP, acc, 0, 0, 0);
                acc = __builtin_amdgcn_mfma_f32_16x16x32_bf16(wSf[kb], bS[kb], acc, 0, 0, 0);
                acc = __builtin_amdgcn_mfma_f32_16x16x32_bf16(wDf[kb], bD[kb], acc, 0, 0, 0);
            }
            // lane (m,q) holds e_pre[ch = t*16+q*4+r][edge = g*16+m]
            float psum = 0.f;
#pragma unroll
            for (int r = 0; r < 4; r++)
                psum = fmaf(gelu_f(acc[r] + be[r]), wa[r], psum);
            psum += __shfl_xor(psum, 16, 64);
            psum += __shfl_xor(psum, 32, 64);
            if (q == 0) partials[(g * 16 + m) * 8 + wave] = psum;
        }
        __syncthreads();  // partials ready; all stage reads complete
        if (wave == 0 && lane < 32) {
            f32x4 p0 = *(const f32x4*)(partials + lane * 8);
            f32x4 p1 = *(const f32x4*)(partials + lane * 8 + 4);
            float s = p0[0] + p0[1] + p0[2] + p0[3] + p1[0] + p1[1] + p1[2] + p1[3] + bout;
            scores[eb + lane] = s > 0.f ? s : 0.2f * s;
        }
    }
}

// ---------------- per-node aggregation over CSR ----------------
__global__ __launch_bounds__(256) void aggregate_kernel(
    const bf16_t* __restrict__ hh,
    const int* __restrict__ offsets, const int* __restrict__ cursor_end,
    const int2* __restrict__ csr,
    bf16_t* __restrict__ neigh, bf16_t* __restrict__ neigh2)
{
    int wave = threadIdx.x >> 6, lane = threadIdx.x & 63;
    int v = blockIdx.x * 4 + wave;
    if (v >= NN) return;
    int off = offsets[v];
    int dg = cursor_end[v] - off;  // cursor[v] == offsets[v] + deg[v] after scatter
    float mx0 = -INFINITY, mx1 = -INFINITY, s0 = 0.f, s1 = 0.f;
    for (int base = 0; base < dg; base += 64) {
        int cnt = dg - base; if (cnt > 64) cnt = 64;
        int s_l = 0; float sc_l = 0.f;
        if (lane < cnt) {
            int2 pk = csr[off + base + lane];
            s_l = pk.x;
            sc_l = __int_as_float(pk.y);
        }
#pragma unroll 8
        for (int i = 0; i < cnt; i++) {
            int s = __shfl(s_l, i, 64);
            float sc = __shfl(sc_l, i, 64);
            bf16x4 hv = *(const bf16x4*)(hh + (size_t)s * 256 + 4 * lane);
            mx0 = fmaxf(mx0, sc * (float)hv[0]);
            mx1 = fmaxf(mx1, sc * (float)hv[1]);
            s0 = fmaf(sc, (float)hv[2], s0);
            s1 = fmaf(sc, (float)hv[3], s1);
        }
    }
    float inv = 1.0f / (float)(dg > 1 ? dg : 1);
    bf16x2 n1, n2;
    n1[0] = (bf16_t)(dg > 0 ? mx0 : 0.0f);
    n1[1] = (bf16_t)(dg > 0 ? mx1 : 0.0f);
    n2[0] = (bf16_t)(s0 * inv);
    n2[1] = (bf16_t)(s1 * inv);
    *(bf16x2*)(neigh + (size_t)v * DD + 2 * lane) = n1;
    *(bf16x2*)(neigh2 + (size_t)v * DD + 2 * lane) = n2;
}

// ---------------- final: self+neigh+neigh2 linears, then 2 MLP layers ----------------
__global__ __launch_bounds__(256) void final_kernel(
    const bf16_t* __restrict__ fb, const bf16_t* __restrict__ neigh, const bf16_t* __restrict__ neigh2,
    const bf16_t* __restrict__ W_self, const bf16_t* __restrict__ W_neigh, const bf16_t* __restrict__ W_neigh2,
    const float* __restrict__ b_rst,
    const bf16_t* __restrict__ W_mlp, const float* __restrict__ b_mlp,
    float* __restrict__ out)
{
    __shared__ __align__(16) float lds[4][16 * 132];
    int wave = threadIdx.x >> 6;
    int wid = blockIdx.x * 4 + wave;
    if (wid >= NN / 16) return;
    int lane = threadIdx.x & 63, n = lane & 15, q = lane >> 4;
    int nb = wid * 16;
    float* L = lds[wave];

    bf16x8 af[4], an[4], am[4];
#pragma unroll
    for (int kb = 0; kb < 4; kb++) {
        size_t o = (size_t)(nb + n) * DD + kb * 32 + q * 8;
        af[kb] = *(const bf16x8*)(fb + o);
        an[kb] = *(const bf16x8*)(neigh + o);
        am[kb] = *(const bf16x8*)(neigh2 + o);
    }
    f32x4 rst[8];
#pragma unroll
    for (int t = 0; t < 8; t++) {
        f32x4 acc = {0.f, 0.f, 0.f, 0.f};
#pragma unroll
        for (int kb = 0; kb < 4; kb++) {
            int wo = (t * 16 + n) * DD + kb * 32 + q * 8;
            acc = __builtin_amdgcn_mfma_f32_16x16x32_bf16(af[kb], *(const bf16x8*)(W_self + wo), acc, 0, 0, 0);
            acc = __builtin_amdgcn_mfma_f32_16x16x32_bf16(an[kb], *(const bf16x8*)(W_neigh + wo), acc, 0, 0, 0);
            acc = __builtin_amdgcn_mfma_f32_16x16x32_bf16(am[kb], *(const bf16x8*)(W_neigh2 + wo), acc, 0, 0, 0);
        }
        float bv = b_rst[t * 16 + n];
#pragma unroll
        for (int r = 0; r < 4; r++) acc[r] += bv;
        rst[t] = acc;
    }

#pragma unroll
    for (int li = 0; li < 2; li++) {
#pragma unroll
        for (int t = 0; t < 8; t++)
#pragma unroll
            for (int r = 0; r < 4; r++)
                L[(q * 4 + r) * 132 + t * 16 + n] = gelu_f(rst[t][r]);
        __builtin_amdgcn_wave_barrier();
        bf16x8 g[4];
#pragma unroll
        for (int kb = 0; kb < 4; kb++) {
            const f32x4* p = (const f32x4*)&L[n * 132 + kb * 32 + q * 8];
            f32x4 x0 = p[0], x1 = p[1];
            bf16x8 gg;
            gg[0] = (bf16_t)x0[0]; gg[1] = (bf16_t)x0[1]; gg[2] = (bf16_t)x0[2]; gg[3] = (bf16_t)x0[3];
            gg[4] = (bf16_t)x1[0]; gg[5] = (bf16_t)x1[1]; gg[6] = (bf16_t)x1[2]; gg[7] = (bf16_t)x1[3];
            g[kb] = gg;
        }
        __builtin_amdgcn_wave_barrier();
        const bf16_t* Wl = W_mlp + li * DD * DD;
#pragma unroll
        for (int t = 0; t < 8; t++) {
            f32x4 acc = {0.f, 0.f, 0.f, 0.f};
#pragma unroll
            for (int kb = 0; kb < 4; kb++) {
                bf16x8 b = *(const bf16x8*)(Wl + (t * 16 + n) * DD + kb * 32 + q * 8);
                acc = __builtin_amdgcn_mfma_f32_16x16x32_bf16(g[kb], b, acc, 0, 0, 0);
            }
            float bm = b_mlp[li * DD + t * 16 + n];
#pragma unroll
            for (int r = 0; r < 4; r++) rst[t][r] += acc[r] + bm;
        }
    }

#pragma unroll
    for (int t = 0; t < 8; t++)
#pragma unroll
        for (int r = 0; r < 4; r++)
            out[(size_t)(nb + q * 4 + r) * DD + t * 16 + n] = rst[t][r];
}

// ---------------- host launch ----------------
extern "C" void kernel_launch(void* const* d_in, const int* in_sizes, int n_in,
                              void* d_out, int out_size, void* d_ws, size_t ws_size,
                              hipStream_t stream)
{
    const float* feat    = (const float*)d_in[0];
    const int*   src     = (const int*)d_in[1];
    const int*   dst     = (const int*)d_in[2];
    const float* W_asrc  = (const float*)d_in[3],  *b_asrc  = (const float*)d_in[4];
    const float* W_adst  = (const float*)d_in[5],  *b_adst  = (const float*)d_in[6];
    const float* W_asub  = (const float*)d_in[7],  *b_asub  = (const float*)d_in[8];
    const float* W_amul  = (const float*)d_in[9],  *b_amul  = (const float*)d_in[10];
    const float* W_aout  = (const float*)d_in[11], *b_aout  = (const float*)d_in[12];
    const float* W_pool  = (const float*)d_in[13], *b_pool  = (const float*)d_in[14];
    const float* W_pool2 = (const float*)d_in[15], *b_pool2 = (const float*)d_in[16];
    const float* W_self  = (const float*)d_in[17], *b_self  = (const float*)d_in[18];
    const float* W_neigh = (const float*)d_in[19], *b_neigh = (const float*)d_in[20];
    const float* W_neigh2= (const float*)d_in[21], *b_neigh2= (const float*)d_in[22];
    const float* W_mlp   = (const float*)d_in[23], *b_mlp   = (const float*)d_in[24];
    float* out = (float*)d_out;

    char* w = (char*)d_ws;
    auto take = [&](size_t bytes) -> void* {
        void* p = (void*)w;
        w += (bytes + 255) & ~(size_t)255;
        return p;
    };
    bf16_t* fb      = (bf16_t*)take((size_t)NN * DD * sizeof(bf16_t));
    bf16_t* neigh   = (bf16_t*)take((size_t)NN * DD * sizeof(bf16_t));
    bf16_t* neigh2  = (bf16_t*)take((size_t)NN * DD * sizeof(bf16_t));
    bf16_t* hh      = (bf16_t*)take((size_t)NN * 256 * sizeof(bf16_t)); // h/h2 interleaved
    float*  scores  = (float*)take((size_t)NE * sizeof(float));
    int*    deg     = (int*)take((size_t)NN * sizeof(int));
    int*    offsets = (int*)take((size_t)NN * sizeof(int));
    int*    cursor  = (int*)take((size_t)NN * sizeof(int));
    int2*   csr     = (int2*)take((size_t)NE * sizeof(int2));
    int*    bsum    = (int*)take(256 * sizeof(int));
    int*    bbase   = (int*)take(256 * sizeof(int));
    bf16_t* W_S     = (bf16_t*)take((size_t)DD * DD * sizeof(bf16_t));
    bf16_t* W_D     = (bf16_t*)take((size_t)DD * DD * sizeof(bf16_t));
    bf16_t* W_amulb = (bf16_t*)take((size_t)DD * DD * sizeof(bf16_t));
    bf16_t* W_poolb = (bf16_t*)take((size_t)DD * DD * sizeof(bf16_t));
    bf16_t* W_pool2b= (bf16_t*)take((size_t)DD * DD * sizeof(bf16_t));
    bf16_t* W_selfb = (bf16_t*)take((size_t)DD * DD * sizeof(bf16_t));
    bf16_t* W_neighb= (bf16_t*)take((size_t)DD * DD * sizeof(bf16_t));
    bf16_t* W_neigh2b=(bf16_t*)take((size_t)DD * DD * sizeof(bf16_t));
    bf16_t* W_mlpb  = (bf16_t*)take((size_t)2 * DD * DD * sizeof(bf16_t));
    float*  b_e     = (float*)take((size_t)DD * sizeof(float));
    float*  b_rst   = (float*)take((size_t)DD * sizeof(float));

    (void)hipMemsetAsync(deg, 0, (size_t)NN * sizeof(int), stream);

    convert_feat_kernel<<<NN * DD / 4 / 256, 256, 0, stream>>>(feat, fb);

    prep_kernel<<<DD * DD / 256, 256, 0, stream>>>(
        W_asrc, b_asrc, W_adst, b_adst, W_asub, b_asub, W_amul, b_amul,
        W_pool, W_pool2, W_self, b_self, W_neigh, b_neigh, W_neigh2, b_neigh2, W_mlp,
        W_S, W_D, W_amulb, W_poolb, W_pool2b, W_selfb, W_neighb, W_neigh2b, W_mlpb,
        b_e, b_rst);

    const int nwaves = NN / 16;                 // 3125
    const int ngrid = (nwaves + 3) / 4;         // 782
    node_linear_kernel<<<ngrid, 256, 0, stream>>>(
        fb, W_poolb, b_pool, W_pool2b, b_pool2, hh);

    hist_kernel<<<(NE + 255) / 256, 256, 0, stream>>>(dst, deg);
    scan1_kernel<<<SCAN_NB, 256, 0, stream>>>(deg, offsets, bsum);
    scan2_kernel<<<1, 256, 0, stream>>>(bsum, bbase);
    scan3_kernel<<<SCAN_NB, 256, 0, stream>>>(bbase, offsets, cursor);

    edge_score_kernel<<<ES_NBLK, 512, 0, stream>>>(
        fb, src, dst, W_amulb, W_S, W_D, W_aout, b_aout, b_e, scores);

    scatter_kernel<<<(NE + 255) / 256, 256, 0, stream>>>(src, dst, scores, cursor, csr);

    aggregate_kernel<<<(NN + 3) / 4, 256, 0, stream>>>(
        hh, offsets, cursor, csr, neigh, neigh2);

    final_kernel<<<ngrid, 256, 0, stream>>>(
        fb, neigh, neigh2, W_selfb, W_neighb, W_neigh2b, b_rst, W_mlpb, b_mlp, out);
}

// Round 8
// 524.371 us; speedup vs baseline: 1.0508x; 1.0508x over previous
//
#include <hip/hip_runtime.h>
#include <cstdint>
#include <cstddef>

#define NN 50000
#define NE 800000
#define DD 128

static_assert(NN % 16 == 0, "node tiles");
static_assert(NE % 16 == 0, "edge tiles");

typedef __bf16 bf16_t;
typedef bf16_t bf16x8 __attribute__((ext_vector_type(8)));
typedef bf16_t bf16x4 __attribute__((ext_vector_type(4)));
typedef bf16_t bf16x2 __attribute__((ext_vector_type(2)));
typedef float f32x4 __attribute__((ext_vector_type(4)));

// fast gelu: x * sigmoid(2*0.79788456*(x+0.044715x^3)) via v_exp_f32 + rcp (~1e-3 abs err)
__device__ __forceinline__ float gelu_f(float x) {
    float u = x * x;
    float t = fmaf(u, -0.1029442445f, -2.3021184019f);  // -(2log2e)*0.79788456*(1+0.044715u)
    float s = __builtin_amdgcn_exp2f(x * t);
    return x * __builtin_amdgcn_rcpf(1.0f + s);
}

// ---------------- feat f32 -> bf16 ----------------
__global__ __launch_bounds__(256) void convert_feat_kernel(
    const float* __restrict__ feat, bf16_t* __restrict__ fb)
{
    int i = blockIdx.x * 256 + threadIdx.x;  // quad index; NN*DD/4 = 1.6M exact
    f32x4 v = ((const f32x4*)feat)[i];
    bf16x4 o;
    o[0] = (bf16_t)v[0]; o[1] = (bf16_t)v[1]; o[2] = (bf16_t)v[2]; o[3] = (bf16_t)v[3];
    ((bf16x4*)fb)[i] = o;
}

// ---------------- prep: combine + convert weights, combine biases ----------------
__global__ __launch_bounds__(256) void prep_kernel(
    const float* __restrict__ W_asrc, const float* __restrict__ b_asrc,
    const float* __restrict__ W_adst, const float* __restrict__ b_adst,
    const float* __restrict__ W_asub, const float* __restrict__ b_asub,
    const float* __restrict__ W_amul, const float* __restrict__ b_amul,
    const float* __restrict__ W_pool, const float* __restrict__ W_pool2,
    const float* __restrict__ W_self, const float* __restrict__ b_self,
    const float* __restrict__ W_neigh, const float* __restrict__ b_neigh,
    const float* __restrict__ W_neigh2, const float* __restrict__ b_neigh2,
    const float* __restrict__ W_mlp,
    bf16_t* __restrict__ W_S, bf16_t* __restrict__ W_D, bf16_t* __restrict__ W_amulb,
    bf16_t* __restrict__ W_poolb, bf16_t* __restrict__ W_pool2b,
    bf16_t* __restrict__ W_selfb, bf16_t* __restrict__ W_neighb, bf16_t* __restrict__ W_neigh2b,
    bf16_t* __restrict__ W_mlpb,
    float* __restrict__ b_e, float* __restrict__ b_rst)
{
    int gid = blockIdx.x * 256 + threadIdx.x;  // 64 blocks * 256 = 16384 = DD*DD
    float sub = W_asub[gid];
    W_S[gid] = (bf16_t)(W_asrc[gid] + sub);
    W_D[gid] = (bf16_t)(W_adst[gid] - sub);
    W_amulb[gid]   = (bf16_t)W_amul[gid];
    W_poolb[gid]   = (bf16_t)W_pool[gid];
    W_pool2b[gid]  = (bf16_t)W_pool2[gid];
    W_selfb[gid]   = (bf16_t)W_self[gid];
    W_neighb[gid]  = (bf16_t)W_neigh[gid];
    W_neigh2b[gid] = (bf16_t)W_neigh2[gid];
    W_mlpb[gid]            = (bf16_t)W_mlp[gid];
    W_mlpb[DD * DD + gid]  = (bf16_t)W_mlp[DD * DD + gid];
    if (gid < DD) {
        b_e[gid]   = b_asub[gid] + b_amul[gid] + b_asrc[gid] + b_adst[gid];
        b_rst[gid] = b_self[gid] + b_neigh[gid] + b_neigh2[gid];
    }
}

// gelu + store interleaved into hh[node][256]: h ch -> (ch/2)*4+(ch&1), h2 -> +2
__device__ __forceinline__ void mm16_store_ilv(
    const bf16x8 a[4], const bf16_t* __restrict__ W, const float* __restrict__ bias,
    bf16_t* __restrict__ hh, int nb, int n, int q, int sub)
{
#pragma unroll
    for (int t = 0; t < 8; t++) {
        f32x4 acc = {0.f, 0.f, 0.f, 0.f};
#pragma unroll
        for (int kb = 0; kb < 4; kb++) {
            bf16x8 b = *(const bf16x8*)(W + (t * 16 + n) * DD + kb * 32 + q * 8);
            acc = __builtin_amdgcn_mfma_f32_16x16x32_bf16(a[kb], b, acc, 0, 0, 0);
        }
        int ch = t * 16 + n;
        int pos = ((ch >> 1) << 2) + (ch & 1) + sub;
        float bv = bias[ch];
#pragma unroll
        for (int r = 0; r < 4; r++)
            hh[(size_t)(nb + q * 4 + r) * 256 + pos] = (bf16_t)gelu_f(acc[r] + bv);
    }
}

// ---------------- per-node linears: h/h2 (interleaved) ----------------
__global__ __launch_bounds__(256) void node_linear_kernel(
    const bf16_t* __restrict__ fb,
    const bf16_t* __restrict__ W_pool, const float* __restrict__ b_pool,
    const bf16_t* __restrict__ W_pool2, const float* __restrict__ b_pool2,
    bf16_t* __restrict__ hh)
{
    int wid = blockIdx.x * 4 + (threadIdx.x >> 6);
    if (wid >= NN / 16) return;
    int lane = threadIdx.x & 63, n = lane & 15, q = lane >> 4;
    int nb = wid * 16;
    bf16x8 a[4];
#pragma unroll
    for (int kb = 0; kb < 4; kb++)
        a[kb] = *(const bf16x8*)(fb + (size_t)(nb + n) * DD + kb * 32 + q * 8);
    mm16_store_ilv(a, W_pool, b_pool, hh, nb, n, q, 0);
    mm16_store_ilv(a, W_pool2, b_pool2, hh, nb, n, q, 2);
}

// ---------------- CSR build ----------------
__global__ __launch_bounds__(256) void hist_kernel(const int* __restrict__ dst, int* __restrict__ deg) {
    int e = blockIdx.x * 256 + threadIdx.x;
    if (e < NE) atomicAdd(&deg[dst[e]], 1);
}

#define SCAN_NB ((NN + 255) / 256)  // 196

__global__ __launch_bounds__(256) void scan1_kernel(const int* __restrict__ deg,
                                                    int* __restrict__ offsets, int* __restrict__ bsum)
{
    __shared__ int tmp[256];
    int t = threadIdx.x, g = blockIdx.x * 256 + t;
    int v = (g < NN) ? deg[g] : 0;
    tmp[t] = v;
    __syncthreads();
#pragma unroll
    for (int d = 1; d < 256; d <<= 1) {
        int x = (t >= d) ? tmp[t - d] : 0;
        __syncthreads();
        tmp[t] += x;
        __syncthreads();
    }
    if (g < NN) offsets[g] = tmp[t] - v;  // local exclusive
    if (t == 255) bsum[blockIdx.x] = tmp[255];
}

__global__ __launch_bounds__(256) void scan2_kernel(const int* __restrict__ bsum, int* __restrict__ bbase)
{
    __shared__ int tmp[256];
    int t = threadIdx.x;
    int v = (t < SCAN_NB) ? bsum[t] : 0;
    tmp[t] = v;
    __syncthreads();
#pragma unroll
    for (int d = 1; d < 256; d <<= 1) {
        int x = (t >= d) ? tmp[t - d] : 0;
        __syncthreads();
        tmp[t] += x;
        __syncthreads();
    }
    if (t < SCAN_NB) bbase[t] = tmp[t] - v;
}

__global__ __launch_bounds__(256) void scan3_kernel(const int* __restrict__ bbase,
                                                    int* __restrict__ offsets, int* __restrict__ cursor)
{
    int g = blockIdx.x * 256 + threadIdx.x;
    if (g < NN) {
        int o = offsets[g] + bbase[blockIdx.x];
        offsets[g] = o;
        cursor[g] = o;
    }
}

// scatter AFTER edge_score: pack {src, score-bits} per CSR slot
__global__ __launch_bounds__(256) void scatter_kernel(
    const int* __restrict__ src, const int* __restrict__ dst, const float* __restrict__ scores,
    int* __restrict__ cursor, int2* __restrict__ csr)
{
    int e = blockIdx.x * 256 + threadIdx.x;
    if (e < NE) {
        int d = dst[e];
        int pos = atomicAdd(&cursor[d], 1);
        int2 pk;
        pk.x = src[e];
        pk.y = __float_as_int(scores[e]);
        csr[pos] = pk;
    }
}

// ---------------- per-edge score: weight-stationary, edge-streaming ----------------
// 512-thread blocks = 8 waves; wave w owns channel tile t=w (16 ch): 12 weight A-frags
// in registers for kernel lifetime. 32-edge tiles (fs/fd/p, p computed ONCE at staging)
// in double-buffered LDS; 2 barriers/iter.
#define ES_NBLK 1250
#define ES_ITERS (NE / 32 / ES_NBLK)   // 20

__global__ __launch_bounds__(512, 4) void edge_score_kernel(
    const bf16_t* __restrict__ fb, const int* __restrict__ src, const int* __restrict__ dst,
    const bf16_t* __restrict__ W_amul, const bf16_t* __restrict__ W_S, const bf16_t* __restrict__ W_D,
    const float* __restrict__ w_aout, const float* __restrict__ b_aout, const float* __restrict__ b_e,
    float* __restrict__ scores)
{
    __shared__ __align__(16) bf16_t sS[2][32 * 136];
    __shared__ __align__(16) bf16_t sDm[2][32 * 136];
    __shared__ __align__(16) bf16_t sP[2][32 * 136];
    __shared__ float partials[32 * 8];  // [edge][wave]
    int tid = threadIdx.x;
    int wave = tid >> 6, lane = tid & 63;
    int m = lane & 15, q = lane >> 4;
    int t = wave;  // this wave's channel tile

    // persistent weight A-frags: lane holds W[ch = t*16+m][k = kb*32+q*8 .. +7]
    bf16x8 wAm[4], wSf[4], wDf[4];
#pragma unroll
    for (int kb = 0; kb < 4; kb++) {
        int wo = (t * 16 + m) * DD + kb * 32 + q * 8;
        wAm[kb] = *(const bf16x8*)(W_amul + wo);
        wSf[kb] = *(const bf16x8*)(W_S + wo);
        wDf[kb] = *(const bf16x8*)(W_D + wo);
    }
    float be[4], wa[4];
#pragma unroll
    for (int r = 0; r < 4; r++) {
        int ch = t * 16 + q * 4 + r;
        be[r] = b_e[ch];
        wa[r] = w_aout[ch];
    }
    float bout = b_aout[0];

    // staging role: thread -> edge sed (0..31), 16B chunk sc_ (0..15)
    int sed = tid >> 4, sc_ = tid & 15;

    // prefetch tile 0
    int e0 = blockIdx.x * 32 + sed;
    int ps = src[e0], pd = dst[e0];
    bf16x8 pfs = *(const bf16x8*)(fb + (size_t)ps * DD + sc_ * 8);
    bf16x8 pfd = *(const bf16x8*)(fb + (size_t)pd * DD + sc_ * 8);

    for (int it = 0; it < ES_ITERS; it++) {
        int buf = it & 1;
        int eb = (blockIdx.x + it * ES_NBLK) * 32;
        bf16x8 pp;
#pragma unroll
        for (int j = 0; j < 8; j++) pp[j] = (bf16_t)((float)pfs[j] * (float)pfd[j]);
        *(bf16x8*)(sS[buf] + sed * 136 + sc_ * 8) = pfs;
        *(bf16x8*)(sDm[buf] + sed * 136 + sc_ * 8) = pfd;
        *(bf16x8*)(sP[buf] + sed * 136 + sc_ * 8) = pp;
        __syncthreads();  // stage visible (also fences prev iter's partials reads)
        // software pipeline: issue next tile's gathers now
        if (it + 1 < ES_ITERS) {
            int e1 = (blockIdx.x + (it + 1) * ES_NBLK) * 32 + sed;
            ps = src[e1]; pd = dst[e1];
            pfs = *(const bf16x8*)(fb + (size_t)ps * DD + sc_ * 8);
            pfd = *(const bf16x8*)(fb + (size_t)pd * DD + sc_ * 8);
        }
        // two 16-edge groups
#pragma unroll
        for (int g = 0; g < 2; g++) {
            bf16x8 bS[4], bD[4], bP[4];
#pragma unroll
            for (int kb = 0; kb < 4; kb++) {
                int off = (g * 16 + m) * 136 + kb * 32 + q * 8;
                bS[kb] = *(const bf16x8*)(sS[buf] + off);
                bD[kb] = *(const bf16x8*)(sDm[buf] + off);
                bP[kb] = *(const bf16x8*)(sP[buf] + off);
            }
            f32x4 acc = {0.f, 0.f, 0.f, 0.f};
#pragma unroll
            for (int kb = 0; kb < 4; kb++) {
                acc = __builtin_amdgcn_mfma_f32_16x16x32_bf16(wAm[kb], bP[kb], acc, 0, 0, 0);
                acc = __builtin_amdgcn_mfma_f32_16x16x32_bf16(wSf[kb], bS[kb], acc, 0, 0, 0);
                acc = __builtin_amdgcn_mfma_f32_16x16x32_bf16(wDf[kb], bD[kb], acc, 0, 0, 0);
            }
            // lane (m,q) holds e_pre[ch = t*16+q*4+r][edge = g*16+m]
            float psum = 0.f;
#pragma unroll
            for (int r = 0; r < 4; r++)
                psum = fmaf(gelu_f(acc[r] + be[r]), wa[r], psum);
            psum += __shfl_xor(psum, 16, 64);
            psum += __shfl_xor(psum, 32, 64);
            if (q == 0) partials[(g * 16 + m) * 8 + wave] = psum;
        }
        __syncthreads();  // partials ready; all stage reads complete
        if (wave == 0 && lane < 32) {
            f32x4 p0 = *(const f32x4*)(partials + lane * 8);
            f32x4 p1 = *(const f32x4*)(partials + lane * 8 + 4);
            float s = p0[0] + p0[1] + p0[2] + p0[3] + p1[0] + p1[1] + p1[2] + p1[3] + bout;
            scores[eb + lane] = s > 0.f ? s : 0.2f * s;
        }
    }
}

// ---------------- per-node aggregation over CSR ----------------
__global__ __launch_bounds__(256) void aggregate_kernel(
    const bf16_t* __restrict__ hh,
    const int* __restrict__ offsets, const int* __restrict__ cursor_end,
    const int2* __restrict__ csr,
    bf16_t* __restrict__ neigh, bf16_t* __restrict__ neigh2)
{
    int wave = threadIdx.x >> 6, lane = threadIdx.x & 63;
    int v = blockIdx.x * 4 + wave;
    if (v >= NN) return;
    int off = offsets[v];
    int dg = cursor_end[v] - off;  // cursor[v] == offsets[v] + deg[v] after scatter
    float mx0 = -INFINITY, mx1 = -INFINITY, s0 = 0.f, s1 = 0.f;
    for (int base = 0; base < dg; base += 64) {
        int cnt = dg - base; if (cnt > 64) cnt = 64;
        int s_l = 0; float sc_l = 0.f;
        if (lane < cnt) {
            int2 pk = csr[off + base + lane];
            s_l = pk.x;
            sc_l = __int_as_float(pk.y);
        }
#pragma unroll 8
        for (int i = 0; i < cnt; i++) {
            int s = __shfl(s_l, i, 64);
            float sc = __shfl(sc_l, i, 64);
            bf16x4 hv = *(const bf16x4*)(hh + (size_t)s * 256 + 4 * lane);
            mx0 = fmaxf(mx0, sc * (float)hv[0]);
            mx1 = fmaxf(mx1, sc * (float)hv[1]);
            s0 = fmaf(sc, (float)hv[2], s0);
            s1 = fmaf(sc, (float)hv[3], s1);
        }
    }
    float inv = 1.0f / (float)(dg > 1 ? dg : 1);
    bf16x2 n1, n2;
    n1[0] = (bf16_t)(dg > 0 ? mx0 : 0.0f);
    n1[1] = (bf16_t)(dg > 0 ? mx1 : 0.0f);
    n2[0] = (bf16_t)(s0 * inv);
    n2[1] = (bf16_t)(s1 * inv);
    *(bf16x2*)(neigh + (size_t)v * DD + 2 * lane) = n1;
    *(bf16x2*)(neigh2 + (size_t)v * DD + 2 * lane) = n2;
}

// ---------------- final: self+neigh+neigh2 linears, then 2 MLP layers ----------------
__global__ __launch_bounds__(256) void final_kernel(
    const bf16_t* __restrict__ fb, const bf16_t* __restrict__ neigh, const bf16_t* __restrict__ neigh2,
    const bf16_t* __restrict__ W_self, const bf16_t* __restrict__ W_neigh, const bf16_t* __restrict__ W_neigh2,
    const float* __restrict__ b_rst,
    const bf16_t* __restrict__ W_mlp, const float* __restrict__ b_mlp,
    float* __restrict__ out)
{
    __shared__ __align__(16) float lds[4][16 * 132];
    int wave = threadIdx.x >> 6;
    int wid = blockIdx.x * 4 + wave;
    if (wid >= NN / 16) return;
    int lane = threadIdx.x & 63, n = lane & 15, q = lane >> 4;
    int nb = wid * 16;
    float* L = lds[wave];

    bf16x8 af[4], an[4], am[4];
#pragma unroll
    for (int kb = 0; kb < 4; kb++) {
        size_t o = (size_t)(nb + n) * DD + kb * 32 + q * 8;
        af[kb] = *(const bf16x8*)(fb + o);
        an[kb] = *(const bf16x8*)(neigh + o);
        am[kb] = *(const bf16x8*)(neigh2 + o);
    }
    f32x4 rst[8];
#pragma unroll
    for (int t = 0; t < 8; t++) {
        f32x4 acc = {0.f, 0.f, 0.f, 0.f};
#pragma unroll
        for (int kb = 0; kb < 4; kb++) {
            int wo = (t * 16 + n) * DD + kb * 32 + q * 8;
            acc = __builtin_amdgcn_mfma_f32_16x16x32_bf16(af[kb], *(const bf16x8*)(W_self + wo), acc, 0, 0, 0);
            acc = __builtin_amdgcn_mfma_f32_16x16x32_bf16(an[kb], *(const bf16x8*)(W_neigh + wo), acc, 0, 0, 0);
            acc = __builtin_amdgcn_mfma_f32_16x16x32_bf16(am[kb], *(const bf16x8*)(W_neigh2 + wo), acc, 0, 0, 0);
        }
        float bv = b_rst[t * 16 + n];
#pragma unroll
        for (int r = 0; r < 4; r++) acc[r] += bv;
        rst[t] = acc;
    }

#pragma unroll
    for (int li = 0; li < 2; li++) {
#pragma unroll
        for (int t = 0; t < 8; t++)
#pragma unroll
            for (int r = 0; r < 4; r++)
                L[(q * 4 + r) * 132 + t * 16 + n] = gelu_f(rst[t][r]);
        __builtin_amdgcn_wave_barrier();
        bf16x8 g[4];
#pragma unroll
        for (int kb = 0; kb < 4; kb++) {
            const f32x4* p = (const f32x4*)&L[n * 132 + kb * 32 + q * 8];
            f32x4 x0 = p[0], x1 = p[1];
            bf16x8 gg;
            gg[0] = (bf16_t)x0[0]; gg[1] = (bf16_t)x0[1]; gg[2] = (bf16_t)x0[2]; gg[3] = (bf16_t)x0[3];
            gg[4] = (bf16_t)x1[0]; gg[5] = (bf16_t)x1[1]; gg[6] = (bf16_t)x1[2]; gg[7] = (bf16_t)x1[3];
            g[kb] = gg;
        }
        __builtin_amdgcn_wave_barrier();
        const bf16_t* Wl = W_mlp + li * DD * DD;
#pragma unroll
        for (int t = 0; t < 8; t++) {
            f32x4 acc = {0.f, 0.f, 0.f, 0.f};
#pragma unroll
            for (int kb = 0; kb < 4; kb++) {
                bf16x8 b = *(const bf16x8*)(Wl + (t * 16 + n) * DD + kb * 32 + q * 8);
                acc = __builtin_amdgcn_mfma_f32_16x16x32_bf16(g[kb], b, acc, 0, 0, 0);
            }
            float bm = b_mlp[li * DD + t * 16 + n];
#pragma unroll
            for (int r = 0; r < 4; r++) rst[t][r] += acc[r] + bm;
        }
    }

#pragma unroll
    for (int t = 0; t < 8; t++)
#pragma unroll
        for (int r = 0; r < 4; r++)
            out[(size_t)(nb + q * 4 + r) * DD + t * 16 + n] = rst[t][r];
}

// ---------------- host launch ----------------
extern "C" void kernel_launch(void* const* d_in, const int* in_sizes, int n_in,
                              void* d_out, int out_size, void* d_ws, size_t ws_size,
                              hipStream_t stream)
{
    const float* feat    = (const float*)d_in[0];
    const int*   src     = (const int*)d_in[1];
    const int*   dst     = (const int*)d_in[2];
    const float* W_asrc  = (const float*)d_in[3],  *b_asrc  = (const float*)d_in[4];
    const float* W_adst  = (const float*)d_in[5],  *b_adst  = (const float*)d_in[6];
    const float* W_asub  = (const float*)d_in[7],  *b_asub  = (const float*)d_in[8];
    const float* W_amul  = (const float*)d_in[9],  *b_amul  = (const float*)d_in[10];
    const float* W_aout  = (const float*)d_in[11], *b_aout  = (const float*)d_in[12];
    const float* W_pool  = (const float*)d_in[13], *b_pool  = (const float*)d_in[14];
    const float* W_pool2 = (const float*)d_in[15], *b_pool2 = (const float*)d_in[16];
    const float* W_self  = (const float*)d_in[17], *b_self  = (const float*)d_in[18];
    const float* W_neigh = (const float*)d_in[19], *b_neigh = (const float*)d_in[20];
    const float* W_neigh2= (const float*)d_in[21], *b_neigh2= (const float*)d_in[22];
    const float* W_mlp   = (const float*)d_in[23], *b_mlp   = (const float*)d_in[24];
    float* out = (float*)d_out;

    char* w = (char*)d_ws;
    auto take = [&](size_t bytes) -> void* {
        void* p = (void*)w;
        w += (bytes + 255) & ~(size_t)255;
        return p;
    };
    bf16_t* fb      = (bf16_t*)take((size_t)NN * DD * sizeof(bf16_t));
    bf16_t* neigh   = (bf16_t*)take((size_t)NN * DD * sizeof(bf16_t));
    bf16_t* neigh2  = (bf16_t*)take((size_t)NN * DD * sizeof(bf16_t));
    bf16_t* hh      = (bf16_t*)take((size_t)NN * 256 * sizeof(bf16_t)); // h/h2 interleaved
    float*  scores  = (float*)take((size_t)NE * sizeof(float));
    int*    deg     = (int*)take((size_t)NN * sizeof(int));
    int*    offsets = (int*)take((size_t)NN * sizeof(int));
    int*    cursor  = (int*)take((size_t)NN * sizeof(int));
    int2*   csr     = (int2*)take((size_t)NE * sizeof(int2));
    int*    bsum    = (int*)take(256 * sizeof(int));
    int*    bbase   = (int*)take(256 * sizeof(int));
    bf16_t* W_S     = (bf16_t*)take((size_t)DD * DD * sizeof(bf16_t));
    bf16_t* W_D     = (bf16_t*)take((size_t)DD * DD * sizeof(bf16_t));
    bf16_t* W_amulb = (bf16_t*)take((size_t)DD * DD * sizeof(bf16_t));
    bf16_t* W_poolb = (bf16_t*)take((size_t)DD * DD * sizeof(bf16_t));
    bf16_t* W_pool2b= (bf16_t*)take((size_t)DD * DD * sizeof(bf16_t));
    bf16_t* W_selfb = (bf16_t*)take((size_t)DD * DD * sizeof(bf16_t));
    bf16_t* W_neighb= (bf16_t*)take((size_t)DD * DD * sizeof(bf16_t));
    bf16_t* W_neigh2b=(bf16_t*)take((size_t)DD * DD * sizeof(bf16_t));
    bf16_t* W_mlpb  = (bf16_t*)take((size_t)2 * DD * DD * sizeof(bf16_t));
    float*  b_e     = (float*)take((size_t)DD * sizeof(float));
    float*  b_rst   = (float*)take((size_t)DD * sizeof(float));

    (void)hipMemsetAsync(deg, 0, (size_t)NN * sizeof(int), stream);

    convert_feat_kernel<<<NN * DD / 4 / 256, 256, 0, stream>>>(feat, fb);

    prep_kernel<<<DD * DD / 256, 256, 0, stream>>>(
        W_asrc, b_asrc, W_adst, b_adst, W_asub, b_asub, W_amul, b_amul,
        W_pool, W_pool2, W_self, b_self, W_neigh, b_neigh, W_neigh2, b_neigh2, W_mlp,
        W_S, W_D, W_amulb, W_poolb, W_pool2b, W_selfb, W_neighb, W_neigh2b, W_mlpb,
        b_e, b_rst);

    const int nwaves = NN / 16;                 // 3125
    const int ngrid = (nwaves + 3) / 4;         // 782
    node_linear_kernel<<<ngrid, 256, 0, stream>>>(
        fb, W_poolb, b_pool, W_pool2b, b_pool2, hh);

    hist_kernel<<<(NE + 255) / 256, 256, 0, stream>>>(dst, deg);
    scan1_kernel<<<SCAN_NB, 256, 0, stream>>>(deg, offsets, bsum);
    scan2_kernel<<<1, 256, 0, stream>>>(bsum, bbase);
    scan3_kernel<<<SCAN_NB, 256, 0, stream>>>(bbase, offsets, cursor);

    edge_score_kernel<<<ES_NBLK, 512, 0, stream>>>(
        fb, src, dst, W_amulb, W_S, W_D, W_aout, b_aout, b_e, scores);

    scatter_kernel<<<(NE + 255) / 256, 256, 0, stream>>>(src, dst, scores, cursor, csr);

    aggregate_kernel<<<(NN + 3) / 4, 256, 0, stream>>>(
        hh, offsets, cursor, csr, neigh, neigh2);

    final_kernel<<<ngrid, 256, 0, stream>>>(
        fb, neigh, neigh2, W_selfb, W_neighb, W_neigh2b, b_rst, W_mlpb, b_mlp, out);
}

// Round 9
// 515.012 us; speedup vs baseline: 1.0699x; 1.0182x over previous
//
#include <hip/hip_runtime.h>
#include <cstdint>
#include <cstddef>

#define NN 50000
#define NE 800000
#define DD 128

static_assert(NN % 16 == 0, "node tiles");
static_assert(NE % 16 == 0, "edge tiles");

typedef __bf16 bf16_t;
typedef bf16_t bf16x8 __attribute__((ext_vector_type(8)));
typedef bf16_t bf16x4 __attribute__((ext_vector_type(4)));
typedef bf16_t bf16x2 __attribute__((ext_vector_type(2)));
typedef float f32x4 __attribute__((ext_vector_type(4)));

// fast gelu: x * sigmoid(2*0.79788456*(x+0.044715x^3)) via v_exp_f32 + rcp (~1e-3 abs err)
__device__ __forceinline__ float gelu_f(float x) {
    float u = x * x;
    float t = fmaf(u, -0.1029442445f, -2.3021184019f);  // -(2log2e)*0.79788456*(1+0.044715u)
    float s = __builtin_amdgcn_exp2f(x * t);
    return x * __builtin_amdgcn_rcpf(1.0f + s);
}

// ---------------- feat f32 -> bf16 ----------------
__global__ __launch_bounds__(256) void convert_feat_kernel(
    const float* __restrict__ feat, bf16_t* __restrict__ fb)
{
    int i = blockIdx.x * 256 + threadIdx.x;  // quad index; NN*DD/4 = 1.6M exact
    f32x4 v = ((const f32x4*)feat)[i];
    bf16x4 o;
    o[0] = (bf16_t)v[0]; o[1] = (bf16_t)v[1]; o[2] = (bf16_t)v[2]; o[3] = (bf16_t)v[3];
    ((bf16x4*)fb)[i] = o;
}

// ---------------- prep: combine + convert weights, combine biases ----------------
__global__ __launch_bounds__(256) void prep_kernel(
    const float* __restrict__ W_asrc, const float* __restrict__ b_asrc,
    const float* __restrict__ W_adst, const float* __restrict__ b_adst,
    const float* __restrict__ W_asub, const float* __restrict__ b_asub,
    const float* __restrict__ W_amul, const float* __restrict__ b_amul,
    const float* __restrict__ W_pool, const float* __restrict__ W_pool2,
    const float* __restrict__ W_self, const float* __restrict__ b_self,
    const float* __restrict__ W_neigh, const float* __restrict__ b_neigh,
    const float* __restrict__ W_neigh2, const float* __restrict__ b_neigh2,
    const float* __restrict__ W_mlp,
    bf16_t* __restrict__ W_S, bf16_t* __restrict__ W_D, bf16_t* __restrict__ W_amulb,
    bf16_t* __restrict__ W_poolb, bf16_t* __restrict__ W_pool2b,
    bf16_t* __restrict__ W_selfb, bf16_t* __restrict__ W_neighb, bf16_t* __restrict__ W_neigh2b,
    bf16_t* __restrict__ W_mlpb,
    float* __restrict__ b_e, float* __restrict__ b_rst)
{
    int gid = blockIdx.x * 256 + threadIdx.x;  // 64 blocks * 256 = 16384 = DD*DD
    float sub = W_asub[gid];
    W_S[gid] = (bf16_t)(W_asrc[gid] + sub);
    W_D[gid] = (bf16_t)(W_adst[gid] - sub);
    W_amulb[gid]   = (bf16_t)W_amul[gid];
    W_poolb[gid]   = (bf16_t)W_pool[gid];
    W_pool2b[gid]  = (bf16_t)W_pool2[gid];
    W_selfb[gid]   = (bf16_t)W_self[gid];
    W_neighb[gid]  = (bf16_t)W_neigh[gid];
    W_neigh2b[gid] = (bf16_t)W_neigh2[gid];
    W_mlpb[gid]            = (bf16_t)W_mlp[gid];
    W_mlpb[DD * DD + gid]  = (bf16_t)W_mlp[DD * DD + gid];
    if (gid < DD) {
        b_e[gid]   = b_asub[gid] + b_amul[gid] + b_asrc[gid] + b_adst[gid];
        b_rst[gid] = b_self[gid] + b_neigh[gid] + b_neigh2[gid];
    }
}

// gelu + store interleaved into hh[node][256]: h ch -> (ch/2)*4+(ch&1), h2 -> +2
__device__ __forceinline__ void mm16_store_ilv(
    const bf16x8 a[4], const bf16_t* __restrict__ W, const float* __restrict__ bias,
    bf16_t* __restrict__ hh, int nb, int n, int q, int sub)
{
#pragma unroll
    for (int t = 0; t < 8; t++) {
        f32x4 acc = {0.f, 0.f, 0.f, 0.f};
#pragma unroll
        for (int kb = 0; kb < 4; kb++) {
            bf16x8 b = *(const bf16x8*)(W + (t * 16 + n) * DD + kb * 32 + q * 8);
            acc = __builtin_amdgcn_mfma_f32_16x16x32_bf16(a[kb], b, acc, 0, 0, 0);
        }
        int ch = t * 16 + n;
        int pos = ((ch >> 1) << 2) + (ch & 1) + sub;
        float bv = bias[ch];
#pragma unroll
        for (int r = 0; r < 4; r++)
            hh[(size_t)(nb + q * 4 + r) * 256 + pos] = (bf16_t)gelu_f(acc[r] + bv);
    }
}

// ---------------- per-node linears: h/h2 (interleaved) ----------------
__global__ __launch_bounds__(256) void node_linear_kernel(
    const bf16_t* __restrict__ fb,
    const bf16_t* __restrict__ W_pool, const float* __restrict__ b_pool,
    const bf16_t* __restrict__ W_pool2, const float* __restrict__ b_pool2,
    bf16_t* __restrict__ hh)
{
    int wid = blockIdx.x * 4 + (threadIdx.x >> 6);
    if (wid >= NN / 16) return;
    int lane = threadIdx.x & 63, n = lane & 15, q = lane >> 4;
    int nb = wid * 16;
    bf16x8 a[4];
#pragma unroll
    for (int kb = 0; kb < 4; kb++)
        a[kb] = *(const bf16x8*)(fb + (size_t)(nb + n) * DD + kb * 32 + q * 8);
    mm16_store_ilv(a, W_pool, b_pool, hh, nb, n, q, 0);
    mm16_store_ilv(a, W_pool2, b_pool2, hh, nb, n, q, 2);
}

// ---------------- CSR build ----------------
__global__ __launch_bounds__(256) void hist_kernel(const int* __restrict__ dst, int* __restrict__ deg) {
    int e = blockIdx.x * 256 + threadIdx.x;
    if (e < NE) atomicAdd(&deg[dst[e]], 1);
}

#define SCAN_NB ((NN + 255) / 256)  // 196

__global__ __launch_bounds__(256) void scan1_kernel(const int* __restrict__ deg,
                                                    int* __restrict__ offsets, int* __restrict__ bsum)
{
    __shared__ int tmp[256];
    int t = threadIdx.x, g = blockIdx.x * 256 + t;
    int v = (g < NN) ? deg[g] : 0;
    tmp[t] = v;
    __syncthreads();
#pragma unroll
    for (int d = 1; d < 256; d <<= 1) {
        int x = (t >= d) ? tmp[t - d] : 0;
        __syncthreads();
        tmp[t] += x;
        __syncthreads();
    }
    if (g < NN) offsets[g] = tmp[t] - v;  // local exclusive
    if (t == 255) bsum[blockIdx.x] = tmp[255];
}

__global__ __launch_bounds__(256) void scan2_kernel(const int* __restrict__ bsum, int* __restrict__ bbase)
{
    __shared__ int tmp[256];
    int t = threadIdx.x;
    int v = (t < SCAN_NB) ? bsum[t] : 0;
    tmp[t] = v;
    __syncthreads();
#pragma unroll
    for (int d = 1; d < 256; d <<= 1) {
        int x = (t >= d) ? tmp[t - d] : 0;
        __syncthreads();
        tmp[t] += x;
        __syncthreads();
    }
    if (t < SCAN_NB) bbase[t] = tmp[t] - v;
}

__global__ __launch_bounds__(256) void scan3_kernel(const int* __restrict__ bbase,
                                                    int* __restrict__ offsets, int* __restrict__ cursor)
{
    int g = blockIdx.x * 256 + threadIdx.x;
    if (g < NN) {
        int o = offsets[g] + bbase[blockIdx.x];
        offsets[g] = o;
        cursor[g] = o;
    }
}

// scatter AFTER edge_score: pack {src, score-bits} per CSR slot
__global__ __launch_bounds__(256) void scatter_kernel(
    const int* __restrict__ src, const int* __restrict__ dst, const float* __restrict__ scores,
    int* __restrict__ cursor, int2* __restrict__ csr)
{
    int e = blockIdx.x * 256 + threadIdx.x;
    if (e < NE) {
        int d = dst[e];
        int pos = atomicAdd(&cursor[d], 1);
        int2 pk;
        pk.x = src[e];
        pk.y = __float_as_int(scores[e]);
        csr[pos] = pk;
    }
}

// ---------------- per-edge score: weight-stationary, edge-streaming ----------------
// 512-thread blocks = 8 waves; wave w owns channel tile t=w (16 ch): 12 weight A-frags
// in registers for kernel lifetime. 32-edge tiles (fs/fd/p, p computed ONCE at staging)
// in double-buffered LDS; 2 barriers/iter.
#define ES_NBLK 1250
#define ES_ITERS (NE / 32 / ES_NBLK)   // 20

__global__ __launch_bounds__(512, 4) void edge_score_kernel(
    const bf16_t* __restrict__ fb, const int* __restrict__ src, const int* __restrict__ dst,
    const bf16_t* __restrict__ W_amul, const bf16_t* __restrict__ W_S, const bf16_t* __restrict__ W_D,
    const float* __restrict__ w_aout, const float* __restrict__ b_aout, const float* __restrict__ b_e,
    float* __restrict__ scores)
{
    __shared__ __align__(16) bf16_t sS[2][32 * 136];
    __shared__ __align__(16) bf16_t sDm[2][32 * 136];
    __shared__ __align__(16) bf16_t sP[2][32 * 136];
    __shared__ float partials[32 * 8];  // [edge][wave]
    int tid = threadIdx.x;
    int wave = tid >> 6, lane = tid & 63;
    int m = lane & 15, q = lane >> 4;
    int t = wave;  // this wave's channel tile

    // persistent weight A-frags: lane holds W[ch = t*16+m][k = kb*32+q*8 .. +7]
    bf16x8 wAm[4], wSf[4], wDf[4];
#pragma unroll
    for (int kb = 0; kb < 4; kb++) {
        int wo = (t * 16 + m) * DD + kb * 32 + q * 8;
        wAm[kb] = *(const bf16x8*)(W_amul + wo);
        wSf[kb] = *(const bf16x8*)(W_S + wo);
        wDf[kb] = *(const bf16x8*)(W_D + wo);
    }
    float be[4], wa[4];
#pragma unroll
    for (int r = 0; r < 4; r++) {
        int ch = t * 16 + q * 4 + r;
        be[r] = b_e[ch];
        wa[r] = w_aout[ch];
    }
    float bout = b_aout[0];

    // staging role: thread -> edge sed (0..31), 16B chunk sc_ (0..15)
    int sed = tid >> 4, sc_ = tid & 15;

    // prefetch tile 0
    int e0 = blockIdx.x * 32 + sed;
    int ps = src[e0], pd = dst[e0];
    bf16x8 pfs = *(const bf16x8*)(fb + (size_t)ps * DD + sc_ * 8);
    bf16x8 pfd = *(const bf16x8*)(fb + (size_t)pd * DD + sc_ * 8);

    for (int it = 0; it < ES_ITERS; it++) {
        int buf = it & 1;
        int eb = (blockIdx.x + it * ES_NBLK) * 32;
        bf16x8 pp;
#pragma unroll
        for (int j = 0; j < 8; j++) pp[j] = (bf16_t)((float)pfs[j] * (float)pfd[j]);
        *(bf16x8*)(sS[buf] + sed * 136 + sc_ * 8) = pfs;
        *(bf16x8*)(sDm[buf] + sed * 136 + sc_ * 8) = pfd;
        *(bf16x8*)(sP[buf] + sed * 136 + sc_ * 8) = pp;
        __syncthreads();  // stage visible (also fences prev iter's partials reads)
        // software pipeline: issue next tile's gathers now
        if (it + 1 < ES_ITERS) {
            int e1 = (blockIdx.x + (it + 1) * ES_NBLK) * 32 + sed;
            ps = src[e1]; pd = dst[e1];
            pfs = *(const bf16x8*)(fb + (size_t)ps * DD + sc_ * 8);
            pfd = *(const bf16x8*)(fb + (size_t)pd * DD + sc_ * 8);
        }
        // two 16-edge groups
#pragma unroll
        for (int g = 0; g < 2; g++) {
            bf16x8 bS[4], bD[4], bP[4];
#pragma unroll
            for (int kb = 0; kb < 4; kb++) {
                int off = (g * 16 + m) * 136 + kb * 32 + q * 8;
                bS[kb] = *(const bf16x8*)(sS[buf] + off);
                bD[kb] = *(const bf16x8*)(sDm[buf] + off);
                bP[kb] = *(const bf16x8*)(sP[buf] + off);
            }
            f32x4 acc = {0.f, 0.f, 0.f, 0.f};
#pragma unroll
            for (int kb = 0; kb < 4; kb++) {
                acc = __builtin_amdgcn_mfma_f32_16x16x32_bf16(wAm[kb], bP[kb], acc, 0, 0, 0);
                acc = __builtin_amdgcn_mfma_f32_16x16x32_bf16(wSf[kb], bS[kb], acc, 0, 0, 0);
                acc = __builtin_amdgcn_mfma_f32_16x16x32_bf16(wDf[kb], bD[kb], acc, 0, 0, 0);
            }
            // lane (m,q) holds e_pre[ch = t*16+q*4+r][edge = g*16+m]
            float psum = 0.f;
#pragma unroll
            for (int r = 0; r < 4; r++)
                psum = fmaf(gelu_f(acc[r] + be[r]), wa[r], psum);
            psum += __shfl_xor(psum, 16, 64);
            psum += __shfl_xor(psum, 32, 64);
            if (q == 0) partials[(g * 16 + m) * 8 + wave] = psum;
        }
        __syncthreads();  // partials ready; all stage reads complete
        if (wave == 0 && lane < 32) {
            f32x4 p0 = *(const f32x4*)(partials + lane * 8);
            f32x4 p1 = *(const f32x4*)(partials + lane * 8 + 4);
            float s = p0[0] + p0[1] + p0[2] + p0[3] + p1[0] + p1[1] + p1[2] + p1[3] + bout;
            scores[eb + lane] = s > 0.f ? s : 0.2f * s;
        }
    }
}

// ---------------- per-node aggregation over CSR ----------------
// 2 edges per wave-iteration: lanes 0-31 take even edges, 32-63 odd. Each lane loads
// one 16B bf16x8 chunk (4 h + 4 h2 channels) -> one dwordx4 per 2 edges instead of
// two dwordx2. Halves cross-lane merge via shfl_xor(32) at the end.
__global__ __launch_bounds__(256) void aggregate_kernel(
    const bf16_t* __restrict__ hh,
    const int* __restrict__ offsets, const int* __restrict__ cursor_end,
    const int2* __restrict__ csr,
    bf16_t* __restrict__ neigh, bf16_t* __restrict__ neigh2)
{
    int wave = threadIdx.x >> 6, lane = threadIdx.x & 63;
    int v = blockIdx.x * 4 + wave;
    if (v >= NN) return;
    int off = offsets[v];
    int dg = cursor_end[v] - off;  // cursor[v] == offsets[v] + deg[v] after scatter
    int half = lane >> 5;   // which edge of the pair
    int cl = lane & 31;     // 16B chunk id within the row
    f32x4 mx = {-INFINITY, -INFINITY, -INFINITY, -INFINITY};
    f32x4 sm = {0.f, 0.f, 0.f, 0.f};
    for (int base = 0; base < dg; base += 64) {
        int cnt = dg - base; if (cnt > 64) cnt = 64;
        int s_l = 0; float sc_l = 0.f;
        if (lane < cnt) {
            int2 pk = csr[off + base + lane];
            s_l = pk.x;
            sc_l = __int_as_float(pk.y);
        }
        int pairs = (cnt + 1) >> 1;
#pragma unroll 4
        for (int i = 0; i < pairs; i++) {
            int idx = 2 * i + half;
            int s = __shfl(s_l, idx, 64);
            float sc = __shfl(sc_l, idx, 64);
            if (idx < cnt) {
                bf16x8 hv = *(const bf16x8*)(hh + (size_t)s * 256 + 8 * cl);
                // h channels 4cl..4cl+3 at hv[0],hv[1],hv[4],hv[5]; h2 at hv[2],hv[3],hv[6],hv[7]
                mx[0] = fmaxf(mx[0], sc * (float)hv[0]);
                mx[1] = fmaxf(mx[1], sc * (float)hv[1]);
                mx[2] = fmaxf(mx[2], sc * (float)hv[4]);
                mx[3] = fmaxf(mx[3], sc * (float)hv[5]);
                sm[0] = fmaf(sc, (float)hv[2], sm[0]);
                sm[1] = fmaf(sc, (float)hv[3], sm[1]);
                sm[2] = fmaf(sc, (float)hv[6], sm[2]);
                sm[3] = fmaf(sc, (float)hv[7], sm[3]);
            }
        }
    }
    // merge the two halves (edges were split across lane halves)
#pragma unroll
    for (int r = 0; r < 4; r++) {
        mx[r] = fmaxf(mx[r], __shfl_xor(mx[r], 32, 64));
        sm[r] += __shfl_xor(sm[r], 32, 64);
    }
    if (half == 0) {
        float inv = 1.0f / (float)(dg > 1 ? dg : 1);
        bf16x4 n1, n2;
#pragma unroll
        for (int r = 0; r < 4; r++) {
            n1[r] = (bf16_t)(dg > 0 ? mx[r] : 0.0f);
            n2[r] = (bf16_t)(sm[r] * inv);
        }
        // channels 4cl..4cl+3 (contiguous in natural channel order)
        *(bf16x4*)(neigh + (size_t)v * DD + 4 * cl) = n1;
        *(bf16x4*)(neigh2 + (size_t)v * DD + 4 * cl) = n2;
    }
}

// ---------------- final: self+neigh+neigh2 linears, then 2 MLP layers ----------------
__global__ __launch_bounds__(256) void final_kernel(
    const bf16_t* __restrict__ fb, const bf16_t* __restrict__ neigh, const bf16_t* __restrict__ neigh2,
    const bf16_t* __restrict__ W_self, const bf16_t* __restrict__ W_neigh, const bf16_t* __restrict__ W_neigh2,
    const float* __restrict__ b_rst,
    const bf16_t* __restrict__ W_mlp, const float* __restrict__ b_mlp,
    float* __restrict__ out)
{
    __shared__ __align__(16) float lds[4][16 * 132];
    int wave = threadIdx.x >> 6;
    int wid = blockIdx.x * 4 + wave;
    if (wid >= NN / 16) return;
    int lane = threadIdx.x & 63, n = lane & 15, q = lane >> 4;
    int nb = wid * 16;
    float* L = lds[wave];

    bf16x8 af[4], an[4], am[4];
#pragma unroll
    for (int kb = 0; kb < 4; kb++) {
        size_t o = (size_t)(nb + n) * DD + kb * 32 + q * 8;
        af[kb] = *(const bf16x8*)(fb + o);
        an[kb] = *(const bf16x8*)(neigh + o);
        am[kb] = *(const bf16x8*)(neigh2 + o);
    }
    f32x4 rst[8];
#pragma unroll
    for (int t = 0; t < 8; t++) {
        f32x4 acc = {0.f, 0.f, 0.f, 0.f};
#pragma unroll
        for (int kb = 0; kb < 4; kb++) {
            int wo = (t * 16 + n) * DD + kb * 32 + q * 8;
            acc = __builtin_amdgcn_mfma_f32_16x16x32_bf16(af[kb], *(const bf16x8*)(W_self + wo), acc, 0, 0, 0);
            acc = __builtin_amdgcn_mfma_f32_16x16x32_bf16(an[kb], *(const bf16x8*)(W_neigh + wo), acc, 0, 0, 0);
            acc = __builtin_amdgcn_mfma_f32_16x16x32_bf16(am[kb], *(const bf16x8*)(W_neigh2 + wo), acc, 0, 0, 0);
        }
        float bv = b_rst[t * 16 + n];
#pragma unroll
        for (int r = 0; r < 4; r++) acc[r] += bv;
        rst[t] = acc;
    }

#pragma unroll
    for (int li = 0; li < 2; li++) {
#pragma unroll
        for (int t = 0; t < 8; t++)
#pragma unroll
            for (int r = 0; r < 4; r++)
                L[(q * 4 + r) * 132 + t * 16 + n] = gelu_f(rst[t][r]);
        __builtin_amdgcn_wave_barrier();
        bf16x8 g[4];
#pragma unroll
        for (int kb = 0; kb < 4; kb++) {
            const f32x4* p = (const f32x4*)&L[n * 132 + kb * 32 + q * 8];
            f32x4 x0 = p[0], x1 = p[1];
            bf16x8 gg;
            gg[0] = (bf16_t)x0[0]; gg[1] = (bf16_t)x0[1]; gg[2] = (bf16_t)x0[2]; gg[3] = (bf16_t)x0[3];
            gg[4] = (bf16_t)x1[0]; gg[5] = (bf16_t)x1[1]; gg[6] = (bf16_t)x1[2]; gg[7] = (bf16_t)x1[3];
            g[kb] = gg;
        }
        __builtin_amdgcn_wave_barrier();
        const bf16_t* Wl = W_mlp + li * DD * DD;
#pragma unroll
        for (int t = 0; t < 8; t++) {
            f32x4 acc = {0.f, 0.f, 0.f, 0.f};
#pragma unroll
            for (int kb = 0; kb < 4; kb++) {
                bf16x8 b = *(const bf16x8*)(Wl + (t * 16 + n) * DD + kb * 32 + q * 8);
                acc = __builtin_amdgcn_mfma_f32_16x16x32_bf16(g[kb], b, acc, 0, 0, 0);
            }
            float bm = b_mlp[li * DD + t * 16 + n];
#pragma unroll
            for (int r = 0; r < 4; r++) rst[t][r] += acc[r] + bm;
        }
    }

#pragma unroll
    for (int t = 0; t < 8; t++)
#pragma unroll
        for (int r = 0; r < 4; r++)
            out[(size_t)(nb + q * 4 + r) * DD + t * 16 + n] = rst[t][r];
}

// ---------------- host launch ----------------
extern "C" void kernel_launch(void* const* d_in, const int* in_sizes, int n_in,
                              void* d_out, int out_size, void* d_ws, size_t ws_size,
                              hipStream_t stream)
{
    const float* feat    = (const float*)d_in[0];
    const int*   src     = (const int*)d_in[1];
    const int*   dst     = (const int*)d_in[2];
    const float* W_asrc  = (const float*)d_in[3],  *b_asrc  = (const float*)d_in[4];
    const float* W_adst  = (const float*)d_in[5],  *b_adst  = (const float*)d_in[6];
    const float* W_asub  = (const float*)d_in[7],  *b_asub  = (const float*)d_in[8];
    const float* W_amul  = (const float*)d_in[9],  *b_amul  = (const float*)d_in[10];
    const float* W_aout  = (const float*)d_in[11], *b_aout  = (const float*)d_in[12];
    const float* W_pool  = (const float*)d_in[13], *b_pool  = (const float*)d_in[14];
    const float* W_pool2 = (const float*)d_in[15], *b_pool2 = (const float*)d_in[16];
    const float* W_self  = (const float*)d_in[17], *b_self  = (const float*)d_in[18];
    const float* W_neigh = (const float*)d_in[19], *b_neigh = (const float*)d_in[20];
    const float* W_neigh2= (const float*)d_in[21], *b_neigh2= (const float*)d_in[22];
    const float* W_mlp   = (const float*)d_in[23], *b_mlp   = (const float*)d_in[24];
    float* out = (float*)d_out;

    char* w = (char*)d_ws;
    auto take = [&](size_t bytes) -> void* {
        void* p = (void*)w;
        w += (bytes + 255) & ~(size_t)255;
        return p;
    };
    bf16_t* fb      = (bf16_t*)take((size_t)NN * DD * sizeof(bf16_t));
    bf16_t* neigh   = (bf16_t*)take((size_t)NN * DD * sizeof(bf16_t));
    bf16_t* neigh2  = (bf16_t*)take((size_t)NN * DD * sizeof(bf16_t));
    bf16_t* hh      = (bf16_t*)take((size_t)NN * 256 * sizeof(bf16_t)); // h/h2 interleaved
    float*  scores  = (float*)take((size_t)NE * sizeof(float));
    int*    deg     = (int*)take((size_t)NN * sizeof(int));
    int*    offsets = (int*)take((size_t)NN * sizeof(int));
    int*    cursor  = (int*)take((size_t)NN * sizeof(int));
    int2*   csr     = (int2*)take((size_t)NE * sizeof(int2));
    int*    bsum    = (int*)take(256 * sizeof(int));
    int*    bbase   = (int*)take(256 * sizeof(int));
    bf16_t* W_S     = (bf16_t*)take((size_t)DD * DD * sizeof(bf16_t));
    bf16_t* W_D     = (bf16_t*)take((size_t)DD * DD * sizeof(bf16_t));
    bf16_t* W_amulb = (bf16_t*)take((size_t)DD * DD * sizeof(bf16_t));
    bf16_t* W_poolb = (bf16_t*)take((size_t)DD * DD * sizeof(bf16_t));
    bf16_t* W_pool2b= (bf16_t*)take((size_t)DD * DD * sizeof(bf16_t));
    bf16_t* W_selfb = (bf16_t*)take((size_t)DD * DD * sizeof(bf16_t));
    bf16_t* W_neighb= (bf16_t*)take((size_t)DD * DD * sizeof(bf16_t));
    bf16_t* W_neigh2b=(bf16_t*)take((size_t)DD * DD * sizeof(bf16_t));
    bf16_t* W_mlpb  = (bf16_t*)take((size_t)2 * DD * DD * sizeof(bf16_t));
    float*  b_e     = (float*)take((size_t)DD * sizeof(float));
    float*  b_rst   = (float*)take((size_t)DD * sizeof(float));

    (void)hipMemsetAsync(deg, 0, (size_t)NN * sizeof(int), stream);

    convert_feat_kernel<<<NN * DD / 4 / 256, 256, 0, stream>>>(feat, fb);

    prep_kernel<<<DD * DD / 256, 256, 0, stream>>>(
        W_asrc, b_asrc, W_adst, b_adst, W_asub, b_asub, W_amul, b_amul,
        W_pool, W_pool2, W_self, b_self, W_neigh, b_neigh, W_neigh2, b_neigh2, W_mlp,
        W_S, W_D, W_amulb, W_poolb, W_pool2b, W_selfb, W_neighb, W_neigh2b, W_mlpb,
        b_e, b_rst);

    const int nwaves = NN / 16;                 // 3125
    const int ngrid = (nwaves + 3) / 4;         // 782
    node_linear_kernel<<<ngrid, 256, 0, stream>>>(
        fb, W_poolb, b_pool, W_pool2b, b_pool2, hh);

    hist_kernel<<<(NE + 255) / 256, 256, 0, stream>>>(dst, deg);
    scan1_kernel<<<SCAN_NB, 256, 0, stream>>>(deg, offsets, bsum);
    scan2_kernel<<<1, 256, 0, stream>>>(bsum, bbase);
    scan3_kernel<<<SCAN_NB, 256, 0, stream>>>(bbase, offsets, cursor);

    edge_score_kernel<<<ES_NBLK, 512, 0, stream>>>(
        fb, src, dst, W_amulb, W_S, W_D, W_aout, b_aout, b_e, scores);

    scatter_kernel<<<(NE + 255) / 256, 256, 0, stream>>>(src, dst, scores, cursor, csr);

    aggregate_kernel<<<(NN + 3) / 4, 256, 0, stream>>>(
        hh, offsets, cursor, csr, neigh, neigh2);

    final_kernel<<<ngrid, 256, 0, stream>>>(
        fb, neigh, neigh2, W_selfb, W_neighb, W_neigh2b, b_rst, W_mlpb, b_mlp, out);
}

// Round 10
// 471.800 us; speedup vs baseline: 1.1679x; 1.0916x over previous
//
#include <hip/hip_runtime.h>
#include <cstdint>
#include <cstddef>

#define NN 50000
#define NE 800000
#define DD 128

static_assert(NN % 16 == 0, "node tiles");
static_assert(NE % 16 == 0, "edge tiles");

typedef __bf16 bf16_t;
typedef bf16_t bf16x8 __attribute__((ext_vector_type(8)));
typedef bf16_t bf16x4 __attribute__((ext_vector_type(4)));
typedef bf16_t bf16x2 __attribute__((ext_vector_type(2)));
typedef float f32x4 __attribute__((ext_vector_type(4)));

// fast gelu: x * sigmoid(2*0.79788456*(x+0.044715x^3)) via v_exp_f32 + rcp (~1e-3 abs err)
__device__ __forceinline__ float gelu_f(float x) {
    float u = x * x;
    float t = fmaf(u, -0.1029442445f, -2.3021184019f);  // -(2log2e)*0.79788456*(1+0.044715u)
    float s = __builtin_amdgcn_exp2f(x * t);
    return x * __builtin_amdgcn_rcpf(1.0f + s);
}

// fragment-major weight index: element (ch,k) -> ((t*4+kb)*64 + lane)*8 + j
// with t=ch>>4, n=ch&15, kb=k>>5, q=(k&31)>>3, j=k&7, lane=q*16+n.
__device__ __forceinline__ int frag_idx(int ch, int k) {
    int t = ch >> 4, n = ch & 15;
    int kb = k >> 5, r = k & 31, q = r >> 3, j = r & 7;
    return ((((t * 4 + kb) * 4 + q) * 16 + n) << 3) + j;
}

// ---------------- feat f32 -> bf16 ----------------
__global__ __launch_bounds__(256) void convert_feat_kernel(
    const float* __restrict__ feat, bf16_t* __restrict__ fb)
{
    int i = blockIdx.x * 256 + threadIdx.x;  // quad index; NN*DD/4 = 1.6M exact
    f32x4 v = ((const f32x4*)feat)[i];
    bf16x4 o;
    o[0] = (bf16_t)v[0]; o[1] = (bf16_t)v[1]; o[2] = (bf16_t)v[2]; o[3] = (bf16_t)v[3];
    ((bf16x4*)fb)[i] = o;
}

// ---------------- prep: combine + convert weights, combine biases ----------------
// W_S/W_D/W_amul: natural row-major bf16 (edge_score loads once per block).
// pool/pool2/self/neigh/neigh2/mlp: fragment-major (coalesced 1KB wave loads).
__global__ __launch_bounds__(256) void prep_kernel(
    const float* __restrict__ W_asrc, const float* __restrict__ b_asrc,
    const float* __restrict__ W_adst, const float* __restrict__ b_adst,
    const float* __restrict__ W_asub, const float* __restrict__ b_asub,
    const float* __restrict__ W_amul, const float* __restrict__ b_amul,
    const float* __restrict__ W_pool, const float* __restrict__ W_pool2,
    const float* __restrict__ W_self, const float* __restrict__ b_self,
    const float* __restrict__ W_neigh, const float* __restrict__ b_neigh,
    const float* __restrict__ W_neigh2, const float* __restrict__ b_neigh2,
    const float* __restrict__ W_mlp,
    bf16_t* __restrict__ W_S, bf16_t* __restrict__ W_D, bf16_t* __restrict__ W_amulb,
    bf16_t* __restrict__ W_poolf, bf16_t* __restrict__ W_pool2f,
    bf16_t* __restrict__ W_selff, bf16_t* __restrict__ W_neighf, bf16_t* __restrict__ W_neigh2f,
    bf16_t* __restrict__ W_mlpf,
    float* __restrict__ b_e, float* __restrict__ b_rst)
{
    int gid = blockIdx.x * 256 + threadIdx.x;  // 64 blocks * 256 = 16384 = DD*DD
    float sub = W_asub[gid];
    W_S[gid] = (bf16_t)(W_asrc[gid] + sub);
    W_D[gid] = (bf16_t)(W_adst[gid] - sub);
    W_amulb[gid] = (bf16_t)W_amul[gid];
    int ch = gid >> 7, k = gid & 127;
    int fi = frag_idx(ch, k);
    W_poolf[fi]   = (bf16_t)W_pool[gid];
    W_pool2f[fi]  = (bf16_t)W_pool2[gid];
    W_selff[fi]   = (bf16_t)W_self[gid];
    W_neighf[fi]  = (bf16_t)W_neigh[gid];
    W_neigh2f[fi] = (bf16_t)W_neigh2[gid];
    W_mlpf[fi]            = (bf16_t)W_mlp[gid];
    W_mlpf[DD * DD + fi]  = (bf16_t)W_mlp[DD * DD + gid];
    if (gid < DD) {
        b_e[gid]   = b_asub[gid] + b_amul[gid] + b_asrc[gid] + b_adst[gid];
        b_rst[gid] = b_self[gid] + b_neigh[gid] + b_neigh2[gid];
    }
}

// gelu + store interleaved into hh[node][256]: h ch -> (ch/2)*4+(ch&1), h2 -> +2
// W in fragment-major layout.
__device__ __forceinline__ void mm16_store_ilv(
    const bf16x8 a[4], const bf16_t* __restrict__ Wf, const float* __restrict__ bias,
    bf16_t* __restrict__ hh, int nb, int n, int q, int lane, int sub)
{
#pragma unroll
    for (int t = 0; t < 8; t++) {
        f32x4 acc = {0.f, 0.f, 0.f, 0.f};
#pragma unroll
        for (int kb = 0; kb < 4; kb++) {
            bf16x8 b = *(const bf16x8*)(Wf + (((t * 4 + kb) * 64 + lane) << 3));
            acc = __builtin_amdgcn_mfma_f32_16x16x32_bf16(a[kb], b, acc, 0, 0, 0);
        }
        int ch = t * 16 + n;
        int pos = ((ch >> 1) << 2) + (ch & 1) + sub;
        float bv = bias[ch];
#pragma unroll
        for (int r = 0; r < 4; r++)
            hh[(size_t)(nb + q * 4 + r) * 256 + pos] = (bf16_t)gelu_f(acc[r] + bv);
    }
}

// ---------------- per-node linears: h/h2 (interleaved) ----------------
__global__ __launch_bounds__(256) void node_linear_kernel(
    const bf16_t* __restrict__ fb,
    const bf16_t* __restrict__ W_poolf, const float* __restrict__ b_pool,
    const bf16_t* __restrict__ W_pool2f, const float* __restrict__ b_pool2,
    bf16_t* __restrict__ hh)
{
    int wid = blockIdx.x * 4 + (threadIdx.x >> 6);
    if (wid >= NN / 16) return;
    int lane = threadIdx.x & 63, n = lane & 15, q = lane >> 4;
    int nb = wid * 16;
    bf16x8 a[4];
#pragma unroll
    for (int kb = 0; kb < 4; kb++)
        a[kb] = *(const bf16x8*)(fb + (size_t)(nb + n) * DD + kb * 32 + q * 8);
    mm16_store_ilv(a, W_poolf, b_pool, hh, nb, n, q, lane, 0);
    mm16_store_ilv(a, W_pool2f, b_pool2, hh, nb, n, q, lane, 2);
}

// ---------------- CSR build ----------------
__global__ __launch_bounds__(256) void hist_kernel(const int* __restrict__ dst, int* __restrict__ deg) {
    int e = blockIdx.x * 256 + threadIdx.x;
    if (e < NE) atomicAdd(&deg[dst[e]], 1);
}

#define SCAN_NB ((NN + 255) / 256)  // 196

__global__ __launch_bounds__(256) void scan1_kernel(const int* __restrict__ deg,
                                                    int* __restrict__ offsets, int* __restrict__ bsum)
{
    __shared__ int tmp[256];
    int t = threadIdx.x, g = blockIdx.x * 256 + t;
    int v = (g < NN) ? deg[g] : 0;
    tmp[t] = v;
    __syncthreads();
#pragma unroll
    for (int d = 1; d < 256; d <<= 1) {
        int x = (t >= d) ? tmp[t - d] : 0;
        __syncthreads();
        tmp[t] += x;
        __syncthreads();
    }
    if (g < NN) offsets[g] = tmp[t] - v;  // local exclusive
    if (t == 255) bsum[blockIdx.x] = tmp[255];
}

__global__ __launch_bounds__(256) void scan2_kernel(const int* __restrict__ bsum, int* __restrict__ bbase)
{
    __shared__ int tmp[256];
    int t = threadIdx.x;
    int v = (t < SCAN_NB) ? bsum[t] : 0;
    tmp[t] = v;
    __syncthreads();
#pragma unroll
    for (int d = 1; d < 256; d <<= 1) {
        int x = (t >= d) ? tmp[t - d] : 0;
        __syncthreads();
        tmp[t] += x;
        __syncthreads();
    }
    if (t < SCAN_NB) bbase[t] = tmp[t] - v;
}

__global__ __launch_bounds__(256) void scan3_kernel(const int* __restrict__ bbase,
                                                    int* __restrict__ offsets, int* __restrict__ cursor)
{
    int g = blockIdx.x * 256 + threadIdx.x;
    if (g < NN) {
        int o = offsets[g] + bbase[blockIdx.x];
        offsets[g] = o;
        cursor[g] = o;
    }
}

// scatter AFTER edge_score: pack {src, score-bits} per CSR slot
__global__ __launch_bounds__(256) void scatter_kernel(
    const int* __restrict__ src, const int* __restrict__ dst, const float* __restrict__ scores,
    int* __restrict__ cursor, int2* __restrict__ csr)
{
    int e = blockIdx.x * 256 + threadIdx.x;
    if (e < NE) {
        int d = dst[e];
        int pos = atomicAdd(&cursor[d], 1);
        int2 pk;
        pk.x = src[e];
        pk.y = __float_as_int(scores[e]);
        csr[pos] = pk;
    }
}

// ---------------- per-edge score: weight-stationary, edge-streaming ----------------
// 512-thread blocks = 8 waves; wave w owns channel tile t=w (16 ch): 12 weight A-frags
// in registers for kernel lifetime. 32-edge tiles (fs/fd/p, p computed ONCE at staging)
// in double-buffered LDS; 2 barriers/iter.
#define ES_NBLK 1250
#define ES_ITERS (NE / 32 / ES_NBLK)   // 20

__global__ __launch_bounds__(512, 4) void edge_score_kernel(
    const bf16_t* __restrict__ fb, const int* __restrict__ src, const int* __restrict__ dst,
    const bf16_t* __restrict__ W_amul, const bf16_t* __restrict__ W_S, const bf16_t* __restrict__ W_D,
    const float* __restrict__ w_aout, const float* __restrict__ b_aout, const float* __restrict__ b_e,
    float* __restrict__ scores)
{
    __shared__ __align__(16) bf16_t sS[2][32 * 136];
    __shared__ __align__(16) bf16_t sDm[2][32 * 136];
    __shared__ __align__(16) bf16_t sP[2][32 * 136];
    __shared__ float partials[32 * 8];  // [edge][wave]
    int tid = threadIdx.x;
    int wave = tid >> 6, lane = tid & 63;
    int m = lane & 15, q = lane >> 4;
    int t = wave;  // this wave's channel tile

    // persistent weight A-frags: lane holds W[ch = t*16+m][k = kb*32+q*8 .. +7]
    bf16x8 wAm[4], wSf[4], wDf[4];
#pragma unroll
    for (int kb = 0; kb < 4; kb++) {
        int wo = (t * 16 + m) * DD + kb * 32 + q * 8;
        wAm[kb] = *(const bf16x8*)(W_amul + wo);
        wSf[kb] = *(const bf16x8*)(W_S + wo);
        wDf[kb] = *(const bf16x8*)(W_D + wo);
    }
    float be[4], wa[4];
#pragma unroll
    for (int r = 0; r < 4; r++) {
        int ch = t * 16 + q * 4 + r;
        be[r] = b_e[ch];
        wa[r] = w_aout[ch];
    }
    float bout = b_aout[0];

    // staging role: thread -> edge sed (0..31), 16B chunk sc_ (0..15)
    int sed = tid >> 4, sc_ = tid & 15;

    // prefetch tile 0
    int e0 = blockIdx.x * 32 + sed;
    int ps = src[e0], pd = dst[e0];
    bf16x8 pfs = *(const bf16x8*)(fb + (size_t)ps * DD + sc_ * 8);
    bf16x8 pfd = *(const bf16x8*)(fb + (size_t)pd * DD + sc_ * 8);

    for (int it = 0; it < ES_ITERS; it++) {
        int buf = it & 1;
        int eb = (blockIdx.x + it * ES_NBLK) * 32;
        bf16x8 pp;
#pragma unroll
        for (int j = 0; j < 8; j++) pp[j] = (bf16_t)((float)pfs[j] * (float)pfd[j]);
        *(bf16x8*)(sS[buf] + sed * 136 + sc_ * 8) = pfs;
        *(bf16x8*)(sDm[buf] + sed * 136 + sc_ * 8) = pfd;
        *(bf16x8*)(sP[buf] + sed * 136 + sc_ * 8) = pp;
        __syncthreads();  // stage visible (also fences prev iter's partials reads)
        // software pipeline: issue next tile's gathers now
        if (it + 1 < ES_ITERS) {
            int e1 = (blockIdx.x + (it + 1) * ES_NBLK) * 32 + sed;
            ps = src[e1]; pd = dst[e1];
            pfs = *(const bf16x8*)(fb + (size_t)ps * DD + sc_ * 8);
            pfd = *(const bf16x8*)(fb + (size_t)pd * DD + sc_ * 8);
        }
        // two 16-edge groups
#pragma unroll
        for (int g = 0; g < 2; g++) {
            bf16x8 bS[4], bD[4], bP[4];
#pragma unroll
            for (int kb = 0; kb < 4; kb++) {
                int off = (g * 16 + m) * 136 + kb * 32 + q * 8;
                bS[kb] = *(const bf16x8*)(sS[buf] + off);
                bD[kb] = *(const bf16x8*)(sDm[buf] + off);
                bP[kb] = *(const bf16x8*)(sP[buf] + off);
            }
            f32x4 acc = {0.f, 0.f, 0.f, 0.f};
#pragma unroll
            for (int kb = 0; kb < 4; kb++) {
                acc = __builtin_amdgcn_mfma_f32_16x16x32_bf16(wAm[kb], bP[kb], acc, 0, 0, 0);
                acc = __builtin_amdgcn_mfma_f32_16x16x32_bf16(wSf[kb], bS[kb], acc, 0, 0, 0);
                acc = __builtin_amdgcn_mfma_f32_16x16x32_bf16(wDf[kb], bD[kb], acc, 0, 0, 0);
            }
            // lane (m,q) holds e_pre[ch = t*16+q*4+r][edge = g*16+m]
            float psum = 0.f;
#pragma unroll
            for (int r = 0; r < 4; r++)
                psum = fmaf(gelu_f(acc[r] + be[r]), wa[r], psum);
            psum += __shfl_xor(psum, 16, 64);
            psum += __shfl_xor(psum, 32, 64);
            if (q == 0) partials[(g * 16 + m) * 8 + wave] = psum;
        }
        __syncthreads();  // partials ready; all stage reads complete
        if (wave == 0 && lane < 32) {
            f32x4 p0 = *(const f32x4*)(partials + lane * 8);
            f32x4 p1 = *(const f32x4*)(partials + lane * 8 + 4);
            float s = p0[0] + p0[1] + p0[2] + p0[3] + p1[0] + p1[1] + p1[2] + p1[3] + bout;
            scores[eb + lane] = s > 0.f ? s : 0.2f * s;
        }
    }
}

// ---------------- per-node aggregation over CSR ----------------
// 2 edges per wave-iteration: lanes 0-31 take even edges, 32-63 odd. Each lane loads
// one 16B bf16x8 chunk (4 h + 4 h2 channels).
__global__ __launch_bounds__(256) void aggregate_kernel(
    const bf16_t* __restrict__ hh,
    const int* __restrict__ offsets, const int* __restrict__ cursor_end,
    const int2* __restrict__ csr,
    bf16_t* __restrict__ neigh, bf16_t* __restrict__ neigh2)
{
    int wave = threadIdx.x >> 6, lane = threadIdx.x & 63;
    int v = blockIdx.x * 4 + wave;
    if (v >= NN) return;
    int off = offsets[v];
    int dg = cursor_end[v] - off;  // cursor[v] == offsets[v] + deg[v] after scatter
    int half = lane >> 5;   // which edge of the pair
    int cl = lane & 31;     // 16B chunk id within the row
    f32x4 mx = {-INFINITY, -INFINITY, -INFINITY, -INFINITY};
    f32x4 sm = {0.f, 0.f, 0.f, 0.f};
    for (int base = 0; base < dg; base += 64) {
        int cnt = dg - base; if (cnt > 64) cnt = 64;
        int s_l = 0; float sc_l = 0.f;
        if (lane < cnt) {
            int2 pk = csr[off + base + lane];
            s_l = pk.x;
            sc_l = __int_as_float(pk.y);
        }
        int pairs = (cnt + 1) >> 1;
#pragma unroll 4
        for (int i = 0; i < pairs; i++) {
            int idx = 2 * i + half;
            int s = __shfl(s_l, idx, 64);
            float sc = __shfl(sc_l, idx, 64);
            if (idx < cnt) {
                bf16x8 hv = *(const bf16x8*)(hh + (size_t)s * 256 + 8 * cl);
                mx[0] = fmaxf(mx[0], sc * (float)hv[0]);
                mx[1] = fmaxf(mx[1], sc * (float)hv[1]);
                mx[2] = fmaxf(mx[2], sc * (float)hv[4]);
                mx[3] = fmaxf(mx[3], sc * (float)hv[5]);
                sm[0] = fmaf(sc, (float)hv[2], sm[0]);
                sm[1] = fmaf(sc, (float)hv[3], sm[1]);
                sm[2] = fmaf(sc, (float)hv[6], sm[2]);
                sm[3] = fmaf(sc, (float)hv[7], sm[3]);
            }
        }
    }
#pragma unroll
    for (int r = 0; r < 4; r++) {
        mx[r] = fmaxf(mx[r], __shfl_xor(mx[r], 32, 64));
        sm[r] += __shfl_xor(sm[r], 32, 64);
    }
    if (half == 0) {
        float inv = 1.0f / (float)(dg > 1 ? dg : 1);
        bf16x4 n1, n2;
#pragma unroll
        for (int r = 0; r < 4; r++) {
            n1[r] = (bf16_t)(dg > 0 ? mx[r] : 0.0f);
            n2[r] = (bf16_t)(sm[r] * inv);
        }
        *(bf16x4*)(neigh + (size_t)v * DD + 4 * cl) = n1;
        *(bf16x4*)(neigh2 + (size_t)v * DD + 4 * cl) = n2;
    }
}

// ---------------- final: self+neigh+neigh2 linears, then 2 MLP layers ----------------
// all weights fragment-major.
__global__ __launch_bounds__(256) void final_kernel(
    const bf16_t* __restrict__ fb, const bf16_t* __restrict__ neigh, const bf16_t* __restrict__ neigh2,
    const bf16_t* __restrict__ W_selff, const bf16_t* __restrict__ W_neighf, const bf16_t* __restrict__ W_neigh2f,
    const float* __restrict__ b_rst,
    const bf16_t* __restrict__ W_mlpf, const float* __restrict__ b_mlp,
    float* __restrict__ out)
{
    __shared__ __align__(16) float lds[4][16 * 132];
    int wave = threadIdx.x >> 6;
    int wid = blockIdx.x * 4 + wave;
    if (wid >= NN / 16) return;
    int lane = threadIdx.x & 63, n = lane & 15, q = lane >> 4;
    int nb = wid * 16;
    float* L = lds[wave];

    bf16x8 af[4], an[4], am[4];
#pragma unroll
    for (int kb = 0; kb < 4; kb++) {
        size_t o = (size_t)(nb + n) * DD + kb * 32 + q * 8;
        af[kb] = *(const bf16x8*)(fb + o);
        an[kb] = *(const bf16x8*)(neigh + o);
        am[kb] = *(const bf16x8*)(neigh2 + o);
    }
    f32x4 rst[8];
#pragma unroll
    for (int t = 0; t < 8; t++) {
        f32x4 acc = {0.f, 0.f, 0.f, 0.f};
#pragma unroll
        for (int kb = 0; kb < 4; kb++) {
            int wo = ((t * 4 + kb) * 64 + lane) << 3;
            acc = __builtin_amdgcn_mfma_f32_16x16x32_bf16(af[kb], *(const bf16x8*)(W_selff + wo), acc, 0, 0, 0);
            acc = __builtin_amdgcn_mfma_f32_16x16x32_bf16(an[kb], *(const bf16x8*)(W_neighf + wo), acc, 0, 0, 0);
            acc = __builtin_amdgcn_mfma_f32_16x16x32_bf16(am[kb], *(const bf16x8*)(W_neigh2f + wo), acc, 0, 0, 0);
        }
        float bv = b_rst[t * 16 + n];
#pragma unroll
        for (int r = 0; r < 4; r++) acc[r] += bv;
        rst[t] = acc;
    }

#pragma unroll
    for (int li = 0; li < 2; li++) {
#pragma unroll
        for (int t = 0; t < 8; t++)
#pragma unroll
            for (int r = 0; r < 4; r++)
                L[(q * 4 + r) * 132 + t * 16 + n] = gelu_f(rst[t][r]);
        __builtin_amdgcn_wave_barrier();
        bf16x8 g[4];
#pragma unroll
        for (int kb = 0; kb < 4; kb++) {
            const f32x4* p = (const f32x4*)&L[n * 132 + kb * 32 + q * 8];
            f32x4 x0 = p[0], x1 = p[1];
            bf16x8 gg;
            gg[0] = (bf16_t)x0[0]; gg[1] = (bf16_t)x0[1]; gg[2] = (bf16_t)x0[2]; gg[3] = (bf16_t)x0[3];
            gg[4] = (bf16_t)x1[0]; gg[5] = (bf16_t)x1[1]; gg[6] = (bf16_t)x1[2]; gg[7] = (bf16_t)x1[3];
            g[kb] = gg;
        }
        __builtin_amdgcn_wave_barrier();
        const bf16_t* Wl = W_mlpf + li * DD * DD;
#pragma unroll
        for (int t = 0; t < 8; t++) {
            f32x4 acc = {0.f, 0.f, 0.f, 0.f};
#pragma unroll
            for (int kb = 0; kb < 4; kb++) {
                bf16x8 b = *(const bf16x8*)(Wl + (((t * 4 + kb) * 64 + lane) << 3));
                acc = __builtin_amdgcn_mfma_f32_16x16x32_bf16(g[kb], b, acc, 0, 0, 0);
            }
            float bm = b_mlp[li * DD + t * 16 + n];
#pragma unroll
            for (int r = 0; r < 4; r++) rst[t][r] += acc[r] + bm;
        }
    }

#pragma unroll
    for (int t = 0; t < 8; t++)
#pragma unroll
        for (int r = 0; r < 4; r++)
            out[(size_t)(nb + q * 4 + r) * DD + t * 16 + n] = rst[t][r];
}

// ---------------- host launch ----------------
extern "C" void kernel_launch(void* const* d_in, const int* in_sizes, int n_in,
                              void* d_out, int out_size, void* d_ws, size_t ws_size,
                              hipStream_t stream)
{
    const float* feat    = (const float*)d_in[0];
    const int*   src     = (const int*)d_in[1];
    const int*   dst     = (const int*)d_in[2];
    const float* W_asrc  = (const float*)d_in[3],  *b_asrc  = (const float*)d_in[4];
    const float* W_adst  = (const float*)d_in[5],  *b_adst  = (const float*)d_in[6];
    const float* W_asub  = (const float*)d_in[7],  *b_asub  = (const float*)d_in[8];
    const float* W_amul  = (const float*)d_in[9],  *b_amul  = (const float*)d_in[10];
    const float* W_aout  = (const float*)d_in[11], *b_aout  = (const float*)d_in[12];
    const float* W_pool  = (const float*)d_in[13], *b_pool  = (const float*)d_in[14];
    const float* W_pool2 = (const float*)d_in[15], *b_pool2 = (const float*)d_in[16];
    const float* W_self  = (const float*)d_in[17], *b_self  = (const float*)d_in[18];
    const float* W_neigh = (const float*)d_in[19], *b_neigh = (const float*)d_in[20];
    const float* W_neigh2= (const float*)d_in[21], *b_neigh2= (const float*)d_in[22];
    const float* W_mlp   = (const float*)d_in[23], *b_mlp   = (const float*)d_in[24];
    float* out = (float*)d_out;

    char* w = (char*)d_ws;
    auto take = [&](size_t bytes) -> void* {
        void* p = (void*)w;
        w += (bytes + 255) & ~(size_t)255;
        return p;
    };
    bf16_t* fb      = (bf16_t*)take((size_t)NN * DD * sizeof(bf16_t));
    bf16_t* neigh   = (bf16_t*)take((size_t)NN * DD * sizeof(bf16_t));
    bf16_t* neigh2  = (bf16_t*)take((size_t)NN * DD * sizeof(bf16_t));
    bf16_t* hh      = (bf16_t*)take((size_t)NN * 256 * sizeof(bf16_t)); // h/h2 interleaved
    float*  scores  = (float*)take((size_t)NE * sizeof(float));
    int*    deg     = (int*)take((size_t)NN * sizeof(int));
    int*    offsets = (int*)take((size_t)NN * sizeof(int));
    int*    cursor  = (int*)take((size_t)NN * sizeof(int));
    int2*   csr     = (int2*)take((size_t)NE * sizeof(int2));
    int*    bsum    = (int*)take(256 * sizeof(int));
    int*    bbase   = (int*)take(256 * sizeof(int));
    bf16_t* W_S     = (bf16_t*)take((size_t)DD * DD * sizeof(bf16_t));
    bf16_t* W_D     = (bf16_t*)take((size_t)DD * DD * sizeof(bf16_t));
    bf16_t* W_amulb = (bf16_t*)take((size_t)DD * DD * sizeof(bf16_t));
    bf16_t* W_poolf = (bf16_t*)take((size_t)DD * DD * sizeof(bf16_t));
    bf16_t* W_pool2f= (bf16_t*)take((size_t)DD * DD * sizeof(bf16_t));
    bf16_t* W_selff = (bf16_t*)take((size_t)DD * DD * sizeof(bf16_t));
    bf16_t* W_neighf= (bf16_t*)take((size_t)DD * DD * sizeof(bf16_t));
    bf16_t* W_neigh2f=(bf16_t*)take((size_t)DD * DD * sizeof(bf16_t));
    bf16_t* W_mlpf  = (bf16_t*)take((size_t)2 * DD * DD * sizeof(bf16_t));
    float*  b_e     = (float*)take((size_t)DD * sizeof(float));
    float*  b_rst   = (float*)take((size_t)DD * sizeof(float));

    (void)hipMemsetAsync(deg, 0, (size_t)NN * sizeof(int), stream);

    convert_feat_kernel<<<NN * DD / 4 / 256, 256, 0, stream>>>(feat, fb);

    prep_kernel<<<DD * DD / 256, 256, 0, stream>>>(
        W_asrc, b_asrc, W_adst, b_adst, W_asub, b_asub, W_amul, b_amul,
        W_pool, W_pool2, W_self, b_self, W_neigh, b_neigh, W_neigh2, b_neigh2, W_mlp,
        W_S, W_D, W_amulb, W_poolf, W_pool2f, W_selff, W_neighf, W_neigh2f, W_mlpf,
        b_e, b_rst);

    const int nwaves = NN / 16;                 // 3125
    const int ngrid = (nwaves + 3) / 4;         // 782
    node_linear_kernel<<<ngrid, 256, 0, stream>>>(
        fb, W_poolf, b_pool, W_pool2f, b_pool2, hh);

    hist_kernel<<<(NE + 255) / 256, 256, 0, stream>>>(dst, deg);
    scan1_kernel<<<SCAN_NB, 256, 0, stream>>>(deg, offsets, bsum);
    scan2_kernel<<<1, 256, 0, stream>>>(bsum, bbase);
    scan3_kernel<<<SCAN_NB, 256, 0, stream>>>(bbase, offsets, cursor);

    edge_score_kernel<<<ES_NBLK, 512, 0, stream>>>(
        fb, src, dst, W_amulb, W_S, W_D, W_aout, b_aout, b_e, scores);

    scatter_kernel<<<(NE + 255) / 256, 256, 0, stream>>>(src, dst, scores, cursor, csr);

    aggregate_kernel<<<(NN + 3) / 4, 256, 0, stream>>>(
        hh, offsets, cursor, csr, neigh, neigh2);

    final_kernel<<<ngrid, 256, 0, stream>>>(
        fb, neigh, neigh2, W_selff, W_neighf, W_neigh2f, b_rst, W_mlpf, b_mlp, out);
}

// Round 11
// 449.549 us; speedup vs baseline: 1.2257x; 1.0495x over previous
//
#include <hip/hip_runtime.h>
#include <cstdint>
#include <cstddef>

#define NN 50000
#define NE 800000
#define DD 128

static_assert(NN % 16 == 0, "node tiles");
static_assert(NE % 16 == 0, "edge tiles");

typedef __bf16 bf16_t;
typedef bf16_t bf16x8 __attribute__((ext_vector_type(8)));
typedef bf16_t bf16x4 __attribute__((ext_vector_type(4)));
typedef bf16_t bf16x2 __attribute__((ext_vector_type(2)));
typedef float f32x4 __attribute__((ext_vector_type(4)));

// fast gelu: x * sigmoid(2*0.79788456*(x+0.044715x^3)) via v_exp_f32 + rcp (~1e-3 abs err)
__device__ __forceinline__ float gelu_f(float x) {
    float u = x * x;
    float t = fmaf(u, -0.1029442445f, -2.3021184019f);  // -(2log2e)*0.79788456*(1+0.044715u)
    float s = __builtin_amdgcn_exp2f(x * t);
    return x * __builtin_amdgcn_rcpf(1.0f + s);
}

// fragment-major weight index: element (ch,k) -> ((t*4+kb)*64 + lane)*8 + j
__device__ __forceinline__ int frag_idx(int ch, int k) {
    int t = ch >> 4, n = ch & 15;
    int kb = k >> 5, r = k & 31, q = r >> 3, j = r & 7;
    return ((((t * 4 + kb) * 4 + q) * 16 + n) << 3) + j;
}

// ---------------- feat f32 -> bf16, fused with degree histogram ----------------
__global__ __launch_bounds__(256) void convert_feat_kernel(
    const float* __restrict__ feat, bf16_t* __restrict__ fb,
    const int* __restrict__ dst, int* __restrict__ deg)
{
    int i = blockIdx.x * 256 + threadIdx.x;  // quad index; NN*DD/4 = 1.6M exact
    f32x4 v = ((const f32x4*)feat)[i];
    bf16x4 o;
    o[0] = (bf16_t)v[0]; o[1] = (bf16_t)v[1]; o[2] = (bf16_t)v[2]; o[3] = (bf16_t)v[3];
    ((bf16x4*)fb)[i] = o;
    if (i < NE) atomicAdd(&deg[dst[i]], 1);
}

// ---------------- prep: combine + convert weights, combine biases ----------------
// W_S/W_D/W_amul: natural row-major bf16 (edge_score loads once per block).
// pool/pool2/self/neigh/neigh2/mlp: fragment-major (coalesced 1KB wave loads).
__global__ __launch_bounds__(256) void prep_kernel(
    const float* __restrict__ W_asrc, const float* __restrict__ b_asrc,
    const float* __restrict__ W_adst, const float* __restrict__ b_adst,
    const float* __restrict__ W_asub, const float* __restrict__ b_asub,
    const float* __restrict__ W_amul, const float* __restrict__ b_amul,
    const float* __restrict__ W_pool, const float* __restrict__ W_pool2,
    const float* __restrict__ W_self, const float* __restrict__ b_self,
    const float* __restrict__ W_neigh, const float* __restrict__ b_neigh,
    const float* __restrict__ W_neigh2, const float* __restrict__ b_neigh2,
    const float* __restrict__ W_mlp,
    bf16_t* __restrict__ W_S, bf16_t* __restrict__ W_D, bf16_t* __restrict__ W_amulb,
    bf16_t* __restrict__ W_poolf, bf16_t* __restrict__ W_pool2f,
    bf16_t* __restrict__ W_selff, bf16_t* __restrict__ W_neighf, bf16_t* __restrict__ W_neigh2f,
    bf16_t* __restrict__ W_mlpf,
    float* __restrict__ b_e, float* __restrict__ b_rst)
{
    int gid = blockIdx.x * 256 + threadIdx.x;  // 64 blocks * 256 = 16384 = DD*DD
    float sub = W_asub[gid];
    W_S[gid] = (bf16_t)(W_asrc[gid] + sub);
    W_D[gid] = (bf16_t)(W_adst[gid] - sub);
    W_amulb[gid] = (bf16_t)W_amul[gid];
    int ch = gid >> 7, k = gid & 127;
    int fi = frag_idx(ch, k);
    W_poolf[fi]   = (bf16_t)W_pool[gid];
    W_pool2f[fi]  = (bf16_t)W_pool2[gid];
    W_selff[fi]   = (bf16_t)W_self[gid];
    W_neighf[fi]  = (bf16_t)W_neigh[gid];
    W_neigh2f[fi] = (bf16_t)W_neigh2[gid];
    W_mlpf[fi]            = (bf16_t)W_mlp[gid];
    W_mlpf[DD * DD + fi]  = (bf16_t)W_mlp[DD * DD + gid];
    if (gid < DD) {
        b_e[gid]   = b_asub[gid] + b_amul[gid] + b_asrc[gid] + b_adst[gid];
        b_rst[gid] = b_self[gid] + b_neigh[gid] + b_neigh2[gid];
    }
}

// gelu + store interleaved into hh[node][256]: h ch -> (ch/2)*4+(ch&1), h2 -> +2
__device__ __forceinline__ void mm16_store_ilv(
    const bf16x8 a[4], const bf16_t* __restrict__ Wf, const float* __restrict__ bias,
    bf16_t* __restrict__ hh, int nb, int n, int q, int lane, int sub)
{
#pragma unroll
    for (int t = 0; t < 8; t++) {
        f32x4 acc = {0.f, 0.f, 0.f, 0.f};
#pragma unroll
        for (int kb = 0; kb < 4; kb++) {
            bf16x8 b = *(const bf16x8*)(Wf + (((t * 4 + kb) * 64 + lane) << 3));
            acc = __builtin_amdgcn_mfma_f32_16x16x32_bf16(a[kb], b, acc, 0, 0, 0);
        }
        int ch = t * 16 + n;
        int pos = ((ch >> 1) << 2) + (ch & 1) + sub;
        float bv = bias[ch];
#pragma unroll
        for (int r = 0; r < 4; r++)
            hh[(size_t)(nb + q * 4 + r) * 256 + pos] = (bf16_t)gelu_f(acc[r] + bv);
    }
}

// ---------------- per-node linears: h/h2 (interleaved) ----------------
__global__ __launch_bounds__(256) void node_linear_kernel(
    const bf16_t* __restrict__ fb,
    const bf16_t* __restrict__ W_poolf, const float* __restrict__ b_pool,
    const bf16_t* __restrict__ W_pool2f, const float* __restrict__ b_pool2,
    bf16_t* __restrict__ hh)
{
    int wid = blockIdx.x * 4 + (threadIdx.x >> 6);
    if (wid >= NN / 16) return;
    int lane = threadIdx.x & 63, n = lane & 15, q = lane >> 4;
    int nb = wid * 16;
    bf16x8 a[4];
#pragma unroll
    for (int kb = 0; kb < 4; kb++)
        a[kb] = *(const bf16x8*)(fb + (size_t)(nb + n) * DD + kb * 32 + q * 8);
    mm16_store_ilv(a, W_poolf, b_pool, hh, nb, n, q, lane, 0);
    mm16_store_ilv(a, W_pool2f, b_pool2, hh, nb, n, q, lane, 2);
}

// ---------------- CSR scan ----------------
#define SCAN_NB ((NN + 255) / 256)  // 196

__global__ __launch_bounds__(256) void scan1_kernel(const int* __restrict__ deg,
                                                    int* __restrict__ offsets, int* __restrict__ bsum)
{
    __shared__ int tmp[256];
    int t = threadIdx.x, g = blockIdx.x * 256 + t;
    int v = (g < NN) ? deg[g] : 0;
    tmp[t] = v;
    __syncthreads();
#pragma unroll
    for (int d = 1; d < 256; d <<= 1) {
        int x = (t >= d) ? tmp[t - d] : 0;
        __syncthreads();
        tmp[t] += x;
        __syncthreads();
    }
    if (g < NN) offsets[g] = tmp[t] - v;  // local exclusive
    if (t == 255) bsum[blockIdx.x] = tmp[255];
}

__global__ __launch_bounds__(256) void scan2_kernel(const int* __restrict__ bsum, int* __restrict__ bbase)
{
    __shared__ int tmp[256];
    int t = threadIdx.x;
    int v = (t < SCAN_NB) ? bsum[t] : 0;
    tmp[t] = v;
    __syncthreads();
#pragma unroll
    for (int d = 1; d < 256; d <<= 1) {
        int x = (t >= d) ? tmp[t - d] : 0;
        __syncthreads();
        tmp[t] += x;
        __syncthreads();
    }
    if (t < SCAN_NB) bbase[t] = tmp[t] - v;
}

__global__ __launch_bounds__(256) void scan3_kernel(const int* __restrict__ bbase,
                                                    int* __restrict__ offsets, int* __restrict__ cursor)
{
    int g = blockIdx.x * 256 + threadIdx.x;
    if (g < NN) {
        int o = offsets[g] + bbase[blockIdx.x];
        offsets[g] = o;
        cursor[g] = o;
    }
}

// ---------------- per-edge score + fused CSR scatter ----------------
// 512-thread blocks = 8 waves; wave w owns channel tile t=w (16 ch): 12 weight A-frags
// in registers for kernel lifetime. 32-edge tiles (fs/fd/p, p computed ONCE at staging)
// in double-buffered LDS; 2 barriers/iter. Wave 0 writes {src, score} straight into
// the CSR slot via cursor atomics (scatter kernel eliminated).
#define ES_NBLK 1250
#define ES_ITERS (NE / 32 / ES_NBLK)   // 20

__global__ __launch_bounds__(512, 4) void edge_score_kernel(
    const bf16_t* __restrict__ fb, const int* __restrict__ src, const int* __restrict__ dst,
    const bf16_t* __restrict__ W_amul, const bf16_t* __restrict__ W_S, const bf16_t* __restrict__ W_D,
    const float* __restrict__ w_aout, const float* __restrict__ b_aout, const float* __restrict__ b_e,
    int* __restrict__ cursor, int2* __restrict__ csr)
{
    __shared__ __align__(16) bf16_t sS[2][32 * 136];
    __shared__ __align__(16) bf16_t sDm[2][32 * 136];
    __shared__ __align__(16) bf16_t sP[2][32 * 136];
    __shared__ float partials[32 * 8];  // [edge][wave]
    int tid = threadIdx.x;
    int wave = tid >> 6, lane = tid & 63;
    int m = lane & 15, q = lane >> 4;
    int t = wave;  // this wave's channel tile

    // persistent weight A-frags: lane holds W[ch = t*16+m][k = kb*32+q*8 .. +7]
    bf16x8 wAm[4], wSf[4], wDf[4];
#pragma unroll
    for (int kb = 0; kb < 4; kb++) {
        int wo = (t * 16 + m) * DD + kb * 32 + q * 8;
        wAm[kb] = *(const bf16x8*)(W_amul + wo);
        wSf[kb] = *(const bf16x8*)(W_S + wo);
        wDf[kb] = *(const bf16x8*)(W_D + wo);
    }
    float be[4], wa[4];
#pragma unroll
    for (int r = 0; r < 4; r++) {
        int ch = t * 16 + q * 4 + r;
        be[r] = b_e[ch];
        wa[r] = w_aout[ch];
    }
    float bout = b_aout[0];

    // staging role: thread -> edge sed (0..31), 16B chunk sc_ (0..15)
    int sed = tid >> 4, sc_ = tid & 15;

    // prefetch tile 0
    int e0 = blockIdx.x * 32 + sed;
    int ps = src[e0], pd = dst[e0];
    bf16x8 pfs = *(const bf16x8*)(fb + (size_t)ps * DD + sc_ * 8);
    bf16x8 pfd = *(const bf16x8*)(fb + (size_t)pd * DD + sc_ * 8);

    for (int it = 0; it < ES_ITERS; it++) {
        int buf = it & 1;
        int eb = (blockIdx.x + it * ES_NBLK) * 32;
        bf16x8 pp;
#pragma unroll
        for (int j = 0; j < 8; j++) pp[j] = (bf16_t)((float)pfs[j] * (float)pfd[j]);
        *(bf16x8*)(sS[buf] + sed * 136 + sc_ * 8) = pfs;
        *(bf16x8*)(sDm[buf] + sed * 136 + sc_ * 8) = pfd;
        *(bf16x8*)(sP[buf] + sed * 136 + sc_ * 8) = pp;
        __syncthreads();  // stage visible (also fences prev iter's partials reads)
        // software pipeline: issue next tile's gathers now
        if (it + 1 < ES_ITERS) {
            int e1 = (blockIdx.x + (it + 1) * ES_NBLK) * 32 + sed;
            ps = src[e1]; pd = dst[e1];
            pfs = *(const bf16x8*)(fb + (size_t)ps * DD + sc_ * 8);
            pfd = *(const bf16x8*)(fb + (size_t)pd * DD + sc_ * 8);
        }
        // two 16-edge groups
#pragma unroll
        for (int g = 0; g < 2; g++) {
            bf16x8 bS[4], bD[4], bP[4];
#pragma unroll
            for (int kb = 0; kb < 4; kb++) {
                int off = (g * 16 + m) * 136 + kb * 32 + q * 8;
                bS[kb] = *(const bf16x8*)(sS[buf] + off);
                bD[kb] = *(const bf16x8*)(sDm[buf] + off);
                bP[kb] = *(const bf16x8*)(sP[buf] + off);
            }
            f32x4 acc = {0.f, 0.f, 0.f, 0.f};
#pragma unroll
            for (int kb = 0; kb < 4; kb++) {
                acc = __builtin_amdgcn_mfma_f32_16x16x32_bf16(wAm[kb], bP[kb], acc, 0, 0, 0);
                acc = __builtin_amdgcn_mfma_f32_16x16x32_bf16(wSf[kb], bS[kb], acc, 0, 0, 0);
                acc = __builtin_amdgcn_mfma_f32_16x16x32_bf16(wDf[kb], bD[kb], acc, 0, 0, 0);
            }
            // lane (m,q) holds e_pre[ch = t*16+q*4+r][edge = g*16+m]
            float psum = 0.f;
#pragma unroll
            for (int r = 0; r < 4; r++)
                psum = fmaf(gelu_f(acc[r] + be[r]), wa[r], psum);
            psum += __shfl_xor(psum, 16, 64);
            psum += __shfl_xor(psum, 32, 64);
            if (q == 0) partials[(g * 16 + m) * 8 + wave] = psum;
        }
        __syncthreads();  // partials ready; all stage reads complete
        if (wave == 0 && lane < 32) {
            int e = eb + lane;
            f32x4 p0 = *(const f32x4*)(partials + lane * 8);
            f32x4 p1 = *(const f32x4*)(partials + lane * 8 + 4);
            float s = p0[0] + p0[1] + p0[2] + p0[3] + p1[0] + p1[1] + p1[2] + p1[3] + bout;
            s = s > 0.f ? s : 0.2f * s;
            // fused scatter: place {src, score} into CSR slot
            int d = dst[e];
            int pos = atomicAdd(&cursor[d], 1);
            int2 pk;
            pk.x = src[e];
            pk.y = __float_as_int(s);
            csr[pos] = pk;
        }
    }
}

// ---------------- per-node aggregation over CSR ----------------
// 2 edges per wave-iteration: lanes 0-31 take even edges, 32-63 odd. Each lane loads
// one 16B bf16x8 chunk (4 h + 4 h2 channels).
__global__ __launch_bounds__(256) void aggregate_kernel(
    const bf16_t* __restrict__ hh,
    const int* __restrict__ offsets, const int* __restrict__ cursor_end,
    const int2* __restrict__ csr,
    bf16_t* __restrict__ neigh, bf16_t* __restrict__ neigh2)
{
    int wave = threadIdx.x >> 6, lane = threadIdx.x & 63;
    int v = blockIdx.x * 4 + wave;
    if (v >= NN) return;
    int off = offsets[v];
    int dg = cursor_end[v] - off;  // cursor[v] == offsets[v] + deg[v] after fused scatter
    int half = lane >> 5;   // which edge of the pair
    int cl = lane & 31;     // 16B chunk id within the row
    f32x4 mx = {-INFINITY, -INFINITY, -INFINITY, -INFINITY};
    f32x4 sm = {0.f, 0.f, 0.f, 0.f};
    for (int base = 0; base < dg; base += 64) {
        int cnt = dg - base; if (cnt > 64) cnt = 64;
        int s_l = 0; float sc_l = 0.f;
        if (lane < cnt) {
            int2 pk = csr[off + base + lane];
            s_l = pk.x;
            sc_l = __int_as_float(pk.y);
        }
        int pairs = (cnt + 1) >> 1;
#pragma unroll 4
        for (int i = 0; i < pairs; i++) {
            int idx = 2 * i + half;
            int s = __shfl(s_l, idx, 64);
            float sc = __shfl(sc_l, idx, 64);
            if (idx < cnt) {
                bf16x8 hv = *(const bf16x8*)(hh + (size_t)s * 256 + 8 * cl);
                mx[0] = fmaxf(mx[0], sc * (float)hv[0]);
                mx[1] = fmaxf(mx[1], sc * (float)hv[1]);
                mx[2] = fmaxf(mx[2], sc * (float)hv[4]);
                mx[3] = fmaxf(mx[3], sc * (float)hv[5]);
                sm[0] = fmaf(sc, (float)hv[2], sm[0]);
                sm[1] = fmaf(sc, (float)hv[3], sm[1]);
                sm[2] = fmaf(sc, (float)hv[6], sm[2]);
                sm[3] = fmaf(sc, (float)hv[7], sm[3]);
            }
        }
    }
#pragma unroll
    for (int r = 0; r < 4; r++) {
        mx[r] = fmaxf(mx[r], __shfl_xor(mx[r], 32, 64));
        sm[r] += __shfl_xor(sm[r], 32, 64);
    }
    if (half == 0) {
        float inv = 1.0f / (float)(dg > 1 ? dg : 1);
        bf16x4 n1, n2;
#pragma unroll
        for (int r = 0; r < 4; r++) {
            n1[r] = (bf16_t)(dg > 0 ? mx[r] : 0.0f);
            n2[r] = (bf16_t)(sm[r] * inv);
        }
        *(bf16x4*)(neigh + (size_t)v * DD + 4 * cl) = n1;
        *(bf16x4*)(neigh2 + (size_t)v * DD + 4 * cl) = n2;
    }
}

// ---------------- final: self+neigh+neigh2 linears, then 2 MLP layers ----------------
__global__ __launch_bounds__(256) void final_kernel(
    const bf16_t* __restrict__ fb, const bf16_t* __restrict__ neigh, const bf16_t* __restrict__ neigh2,
    const bf16_t* __restrict__ W_selff, const bf16_t* __restrict__ W_neighf, const bf16_t* __restrict__ W_neigh2f,
    const float* __restrict__ b_rst,
    const bf16_t* __restrict__ W_mlpf, const float* __restrict__ b_mlp,
    float* __restrict__ out)
{
    __shared__ __align__(16) float lds[4][16 * 132];
    int wave = threadIdx.x >> 6;
    int wid = blockIdx.x * 4 + wave;
    if (wid >= NN / 16) return;
    int lane = threadIdx.x & 63, n = lane & 15, q = lane >> 4;
    int nb = wid * 16;
    float* L = lds[wave];

    bf16x8 af[4], an[4], am[4];
#pragma unroll
    for (int kb = 0; kb < 4; kb++) {
        size_t o = (size_t)(nb + n) * DD + kb * 32 + q * 8;
        af[kb] = *(const bf16x8*)(fb + o);
        an[kb] = *(const bf16x8*)(neigh + o);
        am[kb] = *(const bf16x8*)(neigh2 + o);
    }
    f32x4 rst[8];
#pragma unroll
    for (int t = 0; t < 8; t++) {
        f32x4 acc = {0.f, 0.f, 0.f, 0.f};
#pragma unroll
        for (int kb = 0; kb < 4; kb++) {
            int wo = ((t * 4 + kb) * 64 + lane) << 3;
            acc = __builtin_amdgcn_mfma_f32_16x16x32_bf16(af[kb], *(const bf16x8*)(W_selff + wo), acc, 0, 0, 0);
            acc = __builtin_amdgcn_mfma_f32_16x16x32_bf16(an[kb], *(const bf16x8*)(W_neighf + wo), acc, 0, 0, 0);
            acc = __builtin_amdgcn_mfma_f32_16x16x32_bf16(am[kb], *(const bf16x8*)(W_neigh2f + wo), acc, 0, 0, 0);
        }
        float bv = b_rst[t * 16 + n];
#pragma unroll
        for (int r = 0; r < 4; r++) acc[r] += bv;
        rst[t] = acc;
    }

#pragma unroll
    for (int li = 0; li < 2; li++) {
#pragma unroll
        for (int t = 0; t < 8; t++)
#pragma unroll
            for (int r = 0; r < 4; r++)
                L[(q * 4 + r) * 132 + t * 16 + n] = gelu_f(rst[t][r]);
        __builtin_amdgcn_wave_barrier();
        bf16x8 g[4];
#pragma unroll
        for (int kb = 0; kb < 4; kb++) {
            const f32x4* p = (const f32x4*)&L[n * 132 + kb * 32 + q * 8];
            f32x4 x0 = p[0], x1 = p[1];
            bf16x8 gg;
            gg[0] = (bf16_t)x0[0]; gg[1] = (bf16_t)x0[1]; gg[2] = (bf16_t)x0[2]; gg[3] = (bf16_t)x0[3];
            gg[4] = (bf16_t)x1[0]; gg[5] = (bf16_t)x1[1]; gg[6] = (bf16_t)x1[2]; gg[7] = (bf16_t)x1[3];
            g[kb] = gg;
        }
        __builtin_amdgcn_wave_barrier();
        const bf16_t* Wl = W_mlpf + li * DD * DD;
#pragma unroll
        for (int t = 0; t < 8; t++) {
            f32x4 acc = {0.f, 0.f, 0.f, 0.f};
#pragma unroll
            for (int kb = 0; kb < 4; kb++) {
                bf16x8 b = *(const bf16x8*)(Wl + (((t * 4 + kb) * 64 + lane) << 3));
                acc = __builtin_amdgcn_mfma_f32_16x16x32_bf16(g[kb], b, acc, 0, 0, 0);
            }
            float bm = b_mlp[li * DD + t * 16 + n];
#pragma unroll
            for (int r = 0; r < 4; r++) rst[t][r] += acc[r] + bm;
        }
    }

#pragma unroll
    for (int t = 0; t < 8; t++)
#pragma unroll
        for (int r = 0; r < 4; r++)
            out[(size_t)(nb + q * 4 + r) * DD + t * 16 + n] = rst[t][r];
}

// ---------------- host launch ----------------
extern "C" void kernel_launch(void* const* d_in, const int* in_sizes, int n_in,
                              void* d_out, int out_size, void* d_ws, size_t ws_size,
                              hipStream_t stream)
{
    const float* feat    = (const float*)d_in[0];
    const int*   src     = (const int*)d_in[1];
    const int*   dst     = (const int*)d_in[2];
    const float* W_asrc  = (const float*)d_in[3],  *b_asrc  = (const float*)d_in[4];
    const float* W_adst  = (const float*)d_in[5],  *b_adst  = (const float*)d_in[6];
    const float* W_asub  = (const float*)d_in[7],  *b_asub  = (const float*)d_in[8];
    const float* W_amul  = (const float*)d_in[9],  *b_amul  = (const float*)d_in[10];
    const float* W_aout  = (const float*)d_in[11], *b_aout  = (const float*)d_in[12];
    const float* W_pool  = (const float*)d_in[13], *b_pool  = (const float*)d_in[14];
    const float* W_pool2 = (const float*)d_in[15], *b_pool2 = (const float*)d_in[16];
    const float* W_self  = (const float*)d_in[17], *b_self  = (const float*)d_in[18];
    const float* W_neigh = (const float*)d_in[19], *b_neigh = (const float*)d_in[20];
    const float* W_neigh2= (const float*)d_in[21], *b_neigh2= (const float*)d_in[22];
    const float* W_mlp   = (const float*)d_in[23], *b_mlp   = (const float*)d_in[24];
    float* out = (float*)d_out;

    char* w = (char*)d_ws;
    auto take = [&](size_t bytes) -> void* {
        void* p = (void*)w;
        w += (bytes + 255) & ~(size_t)255;
        return p;
    };
    bf16_t* fb      = (bf16_t*)take((size_t)NN * DD * sizeof(bf16_t));
    bf16_t* neigh   = (bf16_t*)take((size_t)NN * DD * sizeof(bf16_t));
    bf16_t* neigh2  = (bf16_t*)take((size_t)NN * DD * sizeof(bf16_t));
    bf16_t* hh      = (bf16_t*)take((size_t)NN * 256 * sizeof(bf16_t)); // h/h2 interleaved
    int*    deg     = (int*)take((size_t)NN * sizeof(int));
    int*    offsets = (int*)take((size_t)NN * sizeof(int));
    int*    cursor  = (int*)take((size_t)NN * sizeof(int));
    int2*   csr     = (int2*)take((size_t)NE * sizeof(int2));
    int*    bsum    = (int*)take(256 * sizeof(int));
    int*    bbase   = (int*)take(256 * sizeof(int));
    bf16_t* W_S     = (bf16_t*)take((size_t)DD * DD * sizeof(bf16_t));
    bf16_t* W_D     = (bf16_t*)take((size_t)DD * DD * sizeof(bf16_t));
    bf16_t* W_amulb = (bf16_t*)take((size_t)DD * DD * sizeof(bf16_t));
    bf16_t* W_poolf = (bf16_t*)take((size_t)DD * DD * sizeof(bf16_t));
    bf16_t* W_pool2f= (bf16_t*)take((size_t)DD * DD * sizeof(bf16_t));
    bf16_t* W_selff = (bf16_t*)take((size_t)DD * DD * sizeof(bf16_t));
    bf16_t* W_neighf= (bf16_t*)take((size_t)DD * DD * sizeof(bf16_t));
    bf16_t* W_neigh2f=(bf16_t*)take((size_t)DD * DD * sizeof(bf16_t));
    bf16_t* W_mlpf  = (bf16_t*)take((size_t)2 * DD * DD * sizeof(bf16_t));
    float*  b_e     = (float*)take((size_t)DD * sizeof(float));
    float*  b_rst   = (float*)take((size_t)DD * sizeof(float));

    (void)hipMemsetAsync(deg, 0, (size_t)NN * sizeof(int), stream);

    convert_feat_kernel<<<NN * DD / 4 / 256, 256, 0, stream>>>(feat, fb, dst, deg);

    prep_kernel<<<DD * DD / 256, 256, 0, stream>>>(
        W_asrc, b_asrc, W_adst, b_adst, W_asub, b_asub, W_amul, b_amul,
        W_pool, W_pool2, W_self, b_self, W_neigh, b_neigh, W_neigh2, b_neigh2, W_mlp,
        W_S, W_D, W_amulb, W_poolf, W_pool2f, W_selff, W_neighf, W_neigh2f, W_mlpf,
        b_e, b_rst);

    const int nwaves = NN / 16;                 // 3125
    const int ngrid = (nwaves + 3) / 4;         // 782
    node_linear_kernel<<<ngrid, 256, 0, stream>>>(
        fb, W_poolf, b_pool, W_pool2f, b_pool2, hh);

    scan1_kernel<<<SCAN_NB, 256, 0, stream>>>(deg, offsets, bsum);
    scan2_kernel<<<1, 256, 0, stream>>>(bsum, bbase);
    scan3_kernel<<<SCAN_NB, 256, 0, stream>>>(bbase, offsets, cursor);

    edge_score_kernel<<<ES_NBLK, 512, 0, stream>>>(
        fb, src, dst, W_amulb, W_S, W_D, W_aout, b_aout, b_e, cursor, csr);

    aggregate_kernel<<<(NN + 3) / 4, 256, 0, stream>>>(
        hh, offsets, cursor, csr, neigh, neigh2);

    final_kernel<<<ngrid, 256, 0, stream>>>(
        fb, neigh, neigh2, W_selff, W_neighf, W_neigh2f, b_rst, W_mlpf, b_mlp, out);
}